// Round 1
// 272.647 us; speedup vs baseline: 1.0887x; 1.0887x over previous
//
#include <hip/hip_runtime.h>

#define B_  4
#define T_  2048
#define H_  16
#define DM_ 1024
#define DH_ 64
#define RK_ 32

using u16 = unsigned short;
using u32 = unsigned int;
typedef float  floatx4 __attribute__((ext_vector_type(4)));
typedef __bf16 bf16x8  __attribute__((ext_vector_type(8)));
typedef u16    u16x8   __attribute__((ext_vector_type(8)));
typedef u16    u16x4   __attribute__((ext_vector_type(4)));
typedef short  s16x4   __attribute__((ext_vector_type(4)));

#define MFMA16(a,b,c) __builtin_amdgcn_mfma_f32_16x16x32_bf16((a),(b),(c),0,0,0)
// K=16 bf16 MFMA: A/B frag = 4 bf16 (k = quad*4+j), C/D same 16x16 layout
#define MFMA1K(a,b,c) __builtin_amdgcn_mfma_f32_16x16x16bf16_1k((a),(b),(c),0,0,0)

__device__ __forceinline__ u16 f2bf(float f) {
  unsigned u = __float_as_uint(f);
  u += 0x7fffu + ((u >> 16) & 1u);   // RNE
  return (u16)(u >> 16);
}
__device__ __forceinline__ float b2f(u16 h) {
  return __uint_as_float(((unsigned)h) << 16);
}
// RNE pack: (bf16(b)<<16)|bf16(a)
__device__ __forceinline__ u32 pack_bf(float a, float b) {
  u32 ua = __float_as_uint(a); ua += 0x7fffu + ((ua >> 16) & 1u);
  u32 ub = __float_as_uint(b); ub += 0x7fffu + ((ub >> 16) & 1u);
  return __builtin_amdgcn_perm(ub, ua, 0x07060302u);
}
// truncation pack (1 instr) — for P in the hot loop (values > 0)
__device__ __forceinline__ u32 tpack(float a, float b) {
  return __builtin_amdgcn_perm(__float_as_uint(b), __float_as_uint(a), 0x07060302u);
}

// async global->LDS, 16B per lane. LDS dest is wave-uniform base; HW adds lane*16.
__device__ __forceinline__ void async_copy16(const u16* g, const u16* lds_uniform_base) {
  __builtin_amdgcn_global_load_lds(
      (const __attribute__((address_space(1))) unsigned int*)(unsigned long long)g,
      (__attribute__((address_space(3))) unsigned int*)(unsigned int)(unsigned long long)lds_uniform_base,
      16, 0, 0);
}

// ---------------- conversion kernels ----------------
__global__ __launch_bounds__(256) void cvt_x(const float* __restrict__ s,
                                             u16* __restrict__ d, int n4) {
  int i = blockIdx.x * 256 + threadIdx.x;
  if (i >= n4) return;
  float4 v = reinterpret_cast<const float4*>(s)[i];
  u16x4 o = { f2bf(v.x), f2bf(v.y), f2bf(v.z), f2bf(v.w) };
  reinterpret_cast<u16x4*>(d)[i] = o;
}

__global__ __launch_bounds__(256) void cvt_weights(const float* __restrict__ Wq,
                                                   const float* __restrict__ Wk,
                                                   const float* __restrict__ Wv,
                                                   const float* __restrict__ Wo,
                                                   u16* __restrict__ Wcat) {
  int i = blockIdx.x * 256 + threadIdx.x;
  int reg = i >> 18;
  const float* s = (reg == 0) ? Wq : (reg == 1) ? Wk : (reg == 2) ? Wv : Wo;
  int j = i & 262143;
  float4 v = reinterpret_cast<const float4*>(s)[j];
  u16x4 o = { f2bf(v.x), f2bf(v.y), f2bf(v.z), f2bf(v.w) };
  reinterpret_cast<u16x4*>(Wcat)[i] = o;
}

// ---------------- GEMM: C[M,N] = A[M,K] * W[N,K]^T + bias, K=1024 ----------------
template <int OUTF32>
__global__ __launch_bounds__(256, 2) void gemm_bt(const u16* __restrict__ A,
                                                  const u16* __restrict__ W,
                                                  const float* __restrict__ b0,
                                                  const float* __restrict__ b1,
                                                  const float* __restrict__ b2,
                                                  void* __restrict__ Cv, int ldc) {
  __shared__ __align__(16) u16 Al[128 * 32];
  __shared__ __align__(16) u16 Bl[128 * 32];
  const int tid  = threadIdx.x;
  const int lane = tid & 63;
  const int wave = tid >> 6;
  const int quad = lane >> 4;
  const int l16  = lane & 15;
  const int wm   = (wave >> 1) << 6;
  const int wn   = (wave & 1) << 6;
  const int bm   = blockIdx.x * 128;
  const int bn   = blockIdx.y * 128;

  floatx4 acc[4][4];
#pragma unroll
  for (int i = 0; i < 4; i++)
#pragma unroll
    for (int j = 0; j < 4; j++) acc[i][j] = (floatx4){0.f, 0.f, 0.f, 0.f};

  const u16* Ag[2]; const u16* Wg[2]; u16* Alb[2]; u16* Blb[2];
#pragma unroll
  for (int issue = 0; issue < 2; issue++) {
    int c = issue * 256 + tid;
    Ag[issue]  = A + (size_t)(bm + (c >> 2)) * 1024 + (c & 3) * 8;
    Wg[issue]  = W + (size_t)(bn + (c >> 2)) * 1024 + (c & 3) * 8;
    int ub = (issue * 256 + wave * 64) * 8;
    Alb[issue] = Al + ub;
    Blb[issue] = Bl + ub;
  }

  for (int k0 = 0; k0 < 1024; k0 += 32) {
#pragma unroll
    for (int issue = 0; issue < 2; issue++) {
      async_copy16(Ag[issue] + k0, Alb[issue]);
      async_copy16(Wg[issue] + k0, Blb[issue]);
    }
    __syncthreads();
    bf16x8 af[4], bfr[4];
#pragma unroll
    for (int i = 0; i < 4; i++) {
      af[i]  = *reinterpret_cast<const bf16x8*>(Al + (wm + i * 16 + l16) * 32 + quad * 8);
      bfr[i] = *reinterpret_cast<const bf16x8*>(Bl + (wn + i * 16 + l16) * 32 + quad * 8);
    }
#pragma unroll
    for (int mi = 0; mi < 4; mi++)
#pragma unroll
      for (int ni = 0; ni < 4; ni++)
        acc[mi][ni] = MFMA16(af[mi], bfr[ni], acc[mi][ni]);
    __syncthreads();
  }

  const float* bp = (bn < 1024) ? b0 : ((bn < 2048) ? b1 : b2);
#pragma unroll
  for (int ni = 0; ni < 4; ni++) {
    int col = bn + wn + ni * 16 + l16;
    float bias = bp[col & 1023];
#pragma unroll
    for (int mi = 0; mi < 4; mi++)
#pragma unroll
      for (int r = 0; r < 4; r++) {
        int row = bm + wm + mi * 16 + quad * 4 + r;
        float v = acc[mi][ni][r] + bias;
        if (OUTF32)
          reinterpret_cast<float*>(Cv)[(size_t)row * ldc + col] = v;
        else
          reinterpret_cast<u16*>(Cv)[(size_t)row * ldc + col] = f2bf(v);
      }
  }
}

// ---------------- V transpose: vt[bh][d][t] ----------------
__global__ __launch_bounds__(256) void vtrans(const u16* __restrict__ qkv,
                                              u16* __restrict__ vt) {
  const int tb = blockIdx.x;
  const int bh = blockIdx.y;
  const int b = bh >> 4, h = bh & 15;
  __shared__ u16 Vl[64][72];
  const int tid = threadIdx.x;
#pragma unroll
  for (int it = 0; it < 2; it++) {
    int c = it * 256 + tid;
    int t = c >> 3, dc = (c & 7) * 8;
    u16x8 v = *reinterpret_cast<const u16x8*>(
        qkv + (size_t)(b * T_ + tb * 64 + t) * 3072 + 2048 + h * 64 + dc);
    *reinterpret_cast<u16x8*>(&Vl[t][dc]) = v;
  }
  __syncthreads();
#pragma unroll
  for (int it = 0; it < 2; it++) {
    int c = it * 256 + tid;
    int d = c >> 3, tt = (c & 7) * 8;
    u16x8 o;
#pragma unroll
    for (int j = 0; j < 8; j++) o[j] = Vl[tt + j][d];
    *reinterpret_cast<u16x8*>(vt + ((size_t)bh * 64 + d) * T_ + tb * 64 + tt) = o;
  }
}

// ---------------- LSR projection via MFMA ----------------
__global__ __launch_bounds__(256) void lsr_mfma(const u16* __restrict__ qkv,
                                                const float* __restrict__ Wql,
                                                const float* __restrict__ Wkl,
                                                u16* __restrict__ qlr,
                                                u16* __restrict__ klr) {
  const int t0 = blockIdx.x * 128;
  const int bh = blockIdx.y, b = bh >> 4, h = bh & 15;
  const int sel = blockIdx.z;
  const int tid = threadIdx.x, lane = tid & 63, w = tid >> 6;
  const int quad = lane >> 4, l16 = lane & 15;
  __shared__ __align__(16) u16 Al[128 * 64];
  __shared__ __align__(16) u16 Wl[32 * 72];

  const float* Wsrc = (sel ? Wkl : Wql) + h * 2048;
  const float fold = sel ? 1.0f : 0.25506100790944405f;  // (1/sqrt(32))*log2(e)
  {
    float4 a = *reinterpret_cast<const float4*>(Wsrc + tid * 8);
    float4 c = *reinterpret_cast<const float4*>(Wsrc + tid * 8 + 4);
    float vals[8] = {a.x, a.y, a.z, a.w, c.x, c.y, c.z, c.w};
#pragma unroll
    for (int i = 0; i < 8; i++) {
      int idx = tid * 8 + i, d = idx >> 5, r = idx & 31;
      Wl[r * 72 + d] = f2bf(vals[i] * fold);
    }
  }
#pragma unroll
  for (int issue = 0; issue < 4; issue++) {
    int l = issue * 256 + tid;
    int t = l >> 3, ck = l & 7;
    const u16* src = qkv + (size_t)(b * T_ + t0 + t) * 3072 + sel * 1024 + h * 64 +
                     ((ck ^ (t & 7)) * 8);
    async_copy16(src, Al + issue * 2048 + w * 512);
  }
  __syncthreads();

  bf16x8 wf[2][2], af[2][2];
#pragma unroll
  for (int mr = 0; mr < 2; mr++)
#pragma unroll
    for (int c = 0; c < 2; c++)
      wf[mr][c] = *reinterpret_cast<const bf16x8*>(&Wl[(mr * 16 + l16) * 72 + c * 32 + quad * 8]);
#pragma unroll
  for (int i = 0; i < 2; i++) {
    int t = (2 * w + i) * 16 + l16;
#pragma unroll
    for (int c = 0; c < 2; c++)
      af[i][c] = *reinterpret_cast<const bf16x8*>(&Al[t * 64 + (((4 * c + quad) ^ (t & 7)) * 8)]);
  }
  floatx4 acc[2][2];
#pragma unroll
  for (int i = 0; i < 2; i++)
#pragma unroll
    for (int mr = 0; mr < 2; mr++) acc[i][mr] = (floatx4){0.f, 0.f, 0.f, 0.f};
#pragma unroll
  for (int i = 0; i < 2; i++)
#pragma unroll
    for (int mr = 0; mr < 2; mr++)
#pragma unroll
      for (int c = 0; c < 2; c++)
        acc[i][mr] = MFMA16(wf[mr][c], af[i][c], acc[i][mr]);

  u16* outp = sel ? klr : qlr;
#pragma unroll
  for (int i = 0; i < 2; i++) {
    int t = t0 + (2 * w + i) * 16 + l16;
#pragma unroll
    for (int mr = 0; mr < 2; mr++) {
      uint2 pv = { pack_bf(acc[i][mr][0], acc[i][mr][1]),
                   pack_bf(acc[i][mr][2], acc[i][mr][3]) };
      *reinterpret_cast<uint2*>(outp + ((size_t)bh * T_ + t) * 32 + mr * 16 + quad * 4) = pv;
    }
  }
}

// ---------------- flash attention, S^T orientation, register-resident P ----------------
// v2: (a) paired q-tiles (31-p, p) per block -> uniform 33 key-tiles/block, 1024 blocks
//     = exactly 4 blocks/CU all-resident (no triangular drain phase);
//     (b) depth-3 async pipeline for BOTH V and K tiles with counted
//     s_waitcnt vmcnt(3) + raw s_barrier (never drain to 0 mid-loop);
//     (c) K staged via global_load_lds (pair-row XOR swizzle, 2-way free) so the
//     steady-state loop has NO compiler-managed global loads -> manual vmcnt holds.
__global__ __launch_bounds__(256, 4) void attn(const u16* __restrict__ qlr,
                                               const u16* __restrict__ klr,
                                               const u16* __restrict__ vt,
                                               u16* __restrict__ yatt) {
  const int bh = blockIdx.y;
  const int b = bh >> 4, h = bh & 15;
  const int p = blockIdx.x;                       // pair index 0..15
  const int tid = threadIdx.x, lane = tid & 63, w = tid >> 6;
  const int quad = lane >> 4, l16 = lane & 15;

  __shared__ __align__(16) u16 Vt3[3][4096];      // 24 KB: V^T tiles [d=64][64 keys]
  __shared__ __align__(16) u16 Kt3[3][2048];      // 12 KB: K tiles   [64 keys][32 rk]

  const u16* qlr_bh = qlr + (size_t)bh * T_ * RK_;
  const u16* klr_bh = klr + (size_t)bh * T_ * RK_;
  const u16* vt_bh  = vt + (size_t)bh * 64 * T_;

  // hoisted V LDS read offsets: A-frag (nt,dt): d=dt*16+l16, keys nt*16+quad*4..+3
  int voff[4][4];
#pragma unroll
  for (int nt = 0; nt < 4; nt++)
#pragma unroll
    for (int dt = 0; dt < 4; dt++) {
      int d = dt * 16 + l16;
      voff[nt][dt] = d * 64 + (((nt * 2 + (quad >> 1)) ^ (d & 7)) * 8) + (quad & 1) * 4;
    }
  // V staging source offsets (pre-swizzled so linear LDS dest ends up swizzled)
  int soffV[2];
#pragma unroll
  for (int issue = 0; issue < 2; issue++) {
    int L = issue * 256 + tid;
    int d = L >> 3, cg = L & 7;
    soffV[issue] = d * T_ + ((cg ^ (d & 7)) * 8);
  }
  // K staging: LDS viewed as 32 pair-rows (2 keys = 128B) x 8 slots of 16B,
  // slot s holds source slot (s ^ (pr&7)). One issue/wave covers the 4KB tile.
  const int soffK = (w * 8 + (lane >> 3)) * 64 + (((lane & 7) ^ (lane >> 3)) * 8);
  // K read: key k=nt*16+l16, rk slot quad -> koff + nt*512
  const int koff = (l16 >> 1) * 64 + ((((l16 & 1) * 4 + quad) ^ (l16 >> 1)) * 8);
  const int wub = w * 512;

  const floatx4 fzero = {0.f, 0.f, 0.f, 0.f};

  for (int run = 0; run < 2; run++) {
    const int qi = run ? p : 31 - p;              // heavy q-tile first
    const int q0 = qi * 64;
    if (run) __syncthreads();                     // WAR fence before restaging buf0/1

    bf16x8 qf = *reinterpret_cast<const bf16x8*>(
        qlr_bh + (size_t)(q0 + w * 16 + l16) * 32 + quad * 8);

    auto stage = [&](int t, int bi) {             // 3 vmcnt ops per wave
      const u16* vs = vt_bh + t * 64;
      async_copy16(vs + soffV[0], &Vt3[bi][wub]);
      async_copy16(vs + soffV[1], &Vt3[bi][2048 + wub]);
      async_copy16(klr_bh + t * 2048 + soffK, &Kt3[bi][wub]);
    };

    stage(0, 0);
    if (qi >= 1) {
      stage(1, 1);
      asm volatile("s_waitcnt vmcnt(3)" ::: "memory");   // stage(0) landed
    } else {
      asm volatile("s_waitcnt vmcnt(0)" ::: "memory");
    }
    __builtin_amdgcn_s_barrier();
    asm volatile("" ::: "memory");                // no LDS reads hoist above barrier

    floatx4 oacc[4];
#pragma unroll
    for (int i = 0; i < 4; i++) oacc[i] = fzero;
    float rs = 0.f;

    const u16* Vb = &Vt3[0][0];
    const u16* Kb = &Kt3[0][0];
    int cb = 0, sb = 2;

    // ---- full tiles ----
    for (int i = 0; i < qi; i++) {
      const bool do_stage = (i + 2 <= qi);
      if (do_stage) stage(i + 2, sb);

      bf16x8 kf[4];
#pragma unroll
      for (int nt = 0; nt < 4; nt++)
        kf[nt] = *reinterpret_cast<const bf16x8*>(Kb + koff + nt * 512);
      floatx4 sv[4];
#pragma unroll
      for (int nt = 0; nt < 4; nt++) sv[nt] = MFMA16(kf[nt], qf, fzero);

      uint2 pk[4];
#pragma unroll
      for (int nt = 0; nt < 4; nt++) {
        float p0 = __builtin_amdgcn_exp2f(sv[nt][0]);
        float p1 = __builtin_amdgcn_exp2f(sv[nt][1]);
        float p2 = __builtin_amdgcn_exp2f(sv[nt][2]);
        float p3 = __builtin_amdgcn_exp2f(sv[nt][3]);
        rs += (p0 + p1) + (p2 + p3);
        pk[nt].x = tpack(p0, p1);
        pk[nt].y = tpack(p2, p3);
      }
#pragma unroll
      for (int dt = 0; dt < 4; dt++)
#pragma unroll
        for (int nt = 0; nt < 4; nt++) {
          s16x4 vf = *reinterpret_cast<const s16x4*>(Vb + voff[nt][dt]);
          oacc[dt] = MFMA1K(vf, __builtin_bit_cast(s16x4, pk[nt]), oacc[dt]);
        }

      // counted wait: 3 newest (stage(i+2)) may stay in flight; stage(i+1) is done
      if (do_stage) asm volatile("s_waitcnt vmcnt(3)" ::: "memory");
      else          asm volatile("s_waitcnt vmcnt(0)" ::: "memory");
      __builtin_amdgcn_s_barrier();
      asm volatile("" ::: "memory");

      cb = (cb == 2) ? 0 : cb + 1;
      Vb = &Vt3[cb][0];
      Kb = &Kt3[cb][0];
      if (do_stage) sb = (sb == 2) ? 0 : sb + 1;
    }

    // ---- diagonal tile (masked) ----
    {
      bf16x8 kf[4];
#pragma unroll
      for (int nt = 0; nt < 4; nt++)
        kf[nt] = *reinterpret_cast<const bf16x8*>(Kb + koff + nt * 512);
      floatx4 sv[4];
#pragma unroll
      for (int nt = 0; nt < 4; nt++) sv[nt] = MFMA16(kf[nt], qf, fzero);
      const int thr = w * 16 + l16;
      uint2 pk[4];
#pragma unroll
      for (int nt = 0; nt < 4; nt++) {
        float pr[4];
#pragma unroll
        for (int r = 0; r < 4; r++) {
          float e = __builtin_amdgcn_exp2f(sv[nt][r]);
          pr[r] = (nt * 16 + quad * 4 + r <= thr) ? e : 0.f;
        }
        rs += (pr[0] + pr[1]) + (pr[2] + pr[3]);
        pk[nt].x = tpack(pr[0], pr[1]);
        pk[nt].y = tpack(pr[2], pr[3]);
      }
#pragma unroll
      for (int dt = 0; dt < 4; dt++)
#pragma unroll
        for (int nt = 0; nt < 4; nt++) {
          s16x4 vf = *reinterpret_cast<const s16x4*>(Vb + voff[nt][dt]);
          oacc[dt] = MFMA1K(vf, __builtin_bit_cast(s16x4, pk[nt]), oacc[dt]);
        }
    }

    // row-sum across the 4 quads; normalize; store O^T (d = dt*16+quad*4+r, qrow = l16)
    rs += __shfl_xor(rs, 16);
    rs += __shfl_xor(rs, 32);
    float inv = 1.f / rs;
    const int qrow = q0 + w * 16 + l16;
#pragma unroll
    for (int dt = 0; dt < 4; dt++) {
      uint2 ov = { pack_bf(oacc[dt][0] * inv, oacc[dt][1] * inv),
                   pack_bf(oacc[dt][2] * inv, oacc[dt][3] * inv) };
      *reinterpret_cast<uint2*>(
          yatt + (size_t)(b * T_ + qrow) * 1024 + h * 64 + dt * 16 + quad * 4) = ov;
    }
  }
}

// ---------------- launch ----------------
extern "C" void kernel_launch(void* const* d_in, const int* in_sizes, int n_in,
                              void* d_out, int out_size, void* d_ws, size_t ws_size,
                              hipStream_t stream) {
  const float* x   = (const float*)d_in[0];
  const float* Wq  = (const float*)d_in[1];
  const float* bq  = (const float*)d_in[2];
  const float* Wk  = (const float*)d_in[3];
  const float* bk  = (const float*)d_in[4];
  const float* Wv  = (const float*)d_in[5];
  const float* bv  = (const float*)d_in[6];
  const float* Wo  = (const float*)d_in[7];
  const float* bo  = (const float*)d_in[8];
  const float* Wql = (const float*)d_in[9];
  const float* Wkl = (const float*)d_in[10];
  float* out = (float*)d_out;

  char* ws = (char*)d_ws;
  u16* xb   = (u16*)(ws);                    // 8192x1024 bf16 (16 MB) -- reused as vt
  u16* Wcat = (u16*)(ws + 16777216);         // 4096x1024 bf16 (8 MB)
  u16* qkv  = (u16*)(ws + 25165824);         // 8192x3072 bf16 (50 MB)
  u16* qlr  = (u16*)(ws + 75497472);         // 64x2048x32 bf16 (8 MB)
  u16* klr  = (u16*)(ws + 83886080);         // 64x2048x32 bf16 (8 MB)
  u16* yatt = (u16*)(ws + 92274688);         // 8192x1024 bf16 (16 MB)
  u16* vt   = xb;                            // [bh][64][2048] bf16, after gemm0

  cvt_x<<<dim3(8192), 256, 0, stream>>>(x, xb, 2097152);
  cvt_weights<<<dim3(4096), 256, 0, stream>>>(Wq, Wk, Wv, Wo, Wcat);
  gemm_bt<0><<<dim3(64, 24), 256, 0, stream>>>(xb, Wcat, bq, bk, bv, qkv, 3072);
  vtrans<<<dim3(32, 64), 256, 0, stream>>>(qkv, vt);
  lsr_mfma<<<dim3(16, 64, 2), 256, 0, stream>>>(qkv, Wql, Wkl, qlr, klr);
  attn<<<dim3(16, 64), 256, 0, stream>>>(qlr, klr, vt, yatt);
  gemm_bt<1><<<dim3(64, 8), 256, 0, stream>>>(yatt, Wcat + 3145728, bo, bo, bo, out, 1024);
}

// Round 2
// 270.817 us; speedup vs baseline: 1.0961x; 1.0068x over previous
//
#include <hip/hip_runtime.h>

#define B_  4
#define T_  2048
#define H_  16
#define DM_ 1024
#define DH_ 64
#define RK_ 32

using u16 = unsigned short;
using u32 = unsigned int;
typedef float  floatx4 __attribute__((ext_vector_type(4)));
typedef __bf16 bf16x8  __attribute__((ext_vector_type(8)));
typedef u16    u16x8   __attribute__((ext_vector_type(8)));
typedef u16    u16x4   __attribute__((ext_vector_type(4)));
typedef short  s16x4   __attribute__((ext_vector_type(4)));

#define MFMA16(a,b,c) __builtin_amdgcn_mfma_f32_16x16x32_bf16((a),(b),(c),0,0,0)
// K=16 bf16 MFMA: A/B frag = 4 bf16 (k = quad*4+j), C/D same 16x16 layout
#define MFMA1K(a,b,c) __builtin_amdgcn_mfma_f32_16x16x16bf16_1k((a),(b),(c),0,0,0)

__device__ __forceinline__ u16 f2bf(float f) {
  unsigned u = __float_as_uint(f);
  u += 0x7fffu + ((u >> 16) & 1u);   // RNE
  return (u16)(u >> 16);
}
__device__ __forceinline__ float b2f(u16 h) {
  return __uint_as_float(((unsigned)h) << 16);
}
// RNE pack: (bf16(b)<<16)|bf16(a)
__device__ __forceinline__ u32 pack_bf(float a, float b) {
  u32 ua = __float_as_uint(a); ua += 0x7fffu + ((ua >> 16) & 1u);
  u32 ub = __float_as_uint(b); ub += 0x7fffu + ((ub >> 16) & 1u);
  return __builtin_amdgcn_perm(ub, ua, 0x07060302u);
}
// truncation pack (1 instr) — for P in the hot loop (values > 0)
__device__ __forceinline__ u32 tpack(float a, float b) {
  return __builtin_amdgcn_perm(__float_as_uint(b), __float_as_uint(a), 0x07060302u);
}

// async global->LDS, 16B per lane. LDS dest is wave-uniform base; HW adds lane*16.
__device__ __forceinline__ void async_copy16(const u16* g, const u16* lds_uniform_base) {
  __builtin_amdgcn_global_load_lds(
      (const __attribute__((address_space(1))) unsigned int*)(unsigned long long)g,
      (__attribute__((address_space(3))) unsigned int*)(unsigned int)(unsigned long long)lds_uniform_base,
      16, 0, 0);
}

// ---------------- conversion kernels ----------------
__global__ __launch_bounds__(256) void cvt_x(const float* __restrict__ s,
                                             u16* __restrict__ d, int n4) {
  int i = blockIdx.x * 256 + threadIdx.x;
  if (i >= n4) return;
  float4 v = reinterpret_cast<const float4*>(s)[i];
  u16x4 o = { f2bf(v.x), f2bf(v.y), f2bf(v.z), f2bf(v.w) };
  reinterpret_cast<u16x4*>(d)[i] = o;
}

__global__ __launch_bounds__(256) void cvt_weights(const float* __restrict__ Wq,
                                                   const float* __restrict__ Wk,
                                                   const float* __restrict__ Wv,
                                                   const float* __restrict__ Wo,
                                                   u16* __restrict__ Wcat) {
  int i = blockIdx.x * 256 + threadIdx.x;
  int reg = i >> 18;
  const float* s = (reg == 0) ? Wq : (reg == 1) ? Wk : (reg == 2) ? Wv : Wo;
  int j = i & 262143;
  float4 v = reinterpret_cast<const float4*>(s)[j];
  u16x4 o = { f2bf(v.x), f2bf(v.y), f2bf(v.z), f2bf(v.w) };
  reinterpret_cast<u16x4*>(Wcat)[i] = o;
}

// ---------------- GEMM v2: C[M,N] = A[M,K] * W[N,K]^T + bias, K=1024 ----------------
// 128x128 tile, BK=64, double-buffered 64KB LDS with XOR-swizzle (slot ^= row&7, T2):
// conflict-free ds_read_b128 (old layout was 8-way conflicted, 6.3M conflicts/dispatch).
// Stage via global_load_lds with PRE-SWIZZLED global source (linear LDS dest, rule #21).
// Raw s_barrier + vmcnt(0) once per 64-K tile; 2 blocks/CU overlap each other's drains.
// 1D grid with bijective XCD swizzle (T1): each XCD keeps its W panels L2-resident.
template <int OUTF32>
__global__ __launch_bounds__(256, 2) void gemm8(const u16* __restrict__ A,
                                                const u16* __restrict__ W,
                                                const float* __restrict__ b0,
                                                const float* __restrict__ b1,
                                                const float* __restrict__ b2,
                                                void* __restrict__ Cv, int ldc) {
  __shared__ __align__(16) u16 Al[2][8192];   // [buf][128 rows][64 k] swizzled
  __shared__ __align__(16) u16 Bl[2][8192];
  const int tid  = threadIdx.x;
  const int lane = tid & 63;
  const int w    = tid >> 6;
  const int quad = lane >> 4;
  const int l16  = lane & 15;
  const int wm   = (w >> 1) << 6;
  const int wn   = (w & 1) << 6;

  // bijective XCD swizzle (gridDim.x % 8 == 0 for both shapes)
  const int cpx = gridDim.x >> 3;
  const int idx = (blockIdx.x & 7) * cpx + (blockIdx.x >> 3);
  const int bm  = (idx & 63) << 7;            // 64 M-blocks
  const int bn  = (idx >> 6) << 7;            // N-blocks (24 or 8)

  // staging: thread tid covers LDS row (chunk*32 + tid>>3), slot tid&7.
  // source k-slot pre-swizzled so LDS slot s holds source slot s^(row&7).
  const int sr = tid >> 3;
  const int sc = ((tid & 7) ^ (sr & 7)) * 8;
  const u16* Ag = A + (size_t)(bm + sr) * 1024 + sc;
  const u16* Wg = W + (size_t)(bn + sr) * 1024 + sc;

  auto stage = [&](int k0, int bsel) {        // 8 vm ops / tile
#pragma unroll
    for (int j = 0; j < 4; j++)
      async_copy16(Ag + (size_t)j * 32768 + k0, &Al[bsel][j * 2048 + w * 512]);
#pragma unroll
    for (int j = 0; j < 4; j++)
      async_copy16(Wg + (size_t)j * 32768 + k0, &Bl[bsel][j * 2048 + w * 512]);
  };

  // fragment read offsets (u16): row*64 + ((ks*4+quad)^(row&7))*8, row&7 == l16&7
  int aoff[4], boff[4], sl[2];
#pragma unroll
  for (int mi = 0; mi < 4; mi++) aoff[mi] = (wm + mi * 16 + l16) * 64;
#pragma unroll
  for (int ni = 0; ni < 4; ni++) boff[ni] = (wn + ni * 16 + l16) * 64;
  sl[0] = ((0 + quad) ^ (l16 & 7)) * 8;
  sl[1] = ((4 + quad) ^ (l16 & 7)) * 8;

  floatx4 acc[4][4];
#pragma unroll
  for (int i = 0; i < 4; i++)
#pragma unroll
    for (int j = 0; j < 4; j++) acc[i][j] = (floatx4){0.f, 0.f, 0.f, 0.f};

  stage(0, 0);
  asm volatile("s_waitcnt vmcnt(0)" ::: "memory");
  __builtin_amdgcn_s_barrier();
  asm volatile("" ::: "memory");

  for (int i = 0; i < 16; i++) {
    if (i < 15) stage((i + 1) * 64, (i + 1) & 1);
    const u16* Ab = Al[i & 1];
    const u16* Bb = Bl[i & 1];
#pragma unroll
    for (int ks = 0; ks < 2; ks++) {
      bf16x8 af[4], bfr[4];
#pragma unroll
      for (int mi = 0; mi < 4; mi++)
        af[mi] = *reinterpret_cast<const bf16x8*>(Ab + aoff[mi] + sl[ks]);
#pragma unroll
      for (int ni = 0; ni < 4; ni++)
        bfr[ni] = *reinterpret_cast<const bf16x8*>(Bb + boff[ni] + sl[ks]);
      __builtin_amdgcn_s_setprio(1);
#pragma unroll
      for (int mi = 0; mi < 4; mi++)
#pragma unroll
        for (int ni = 0; ni < 4; ni++)
          acc[mi][ni] = MFMA16(af[mi], bfr[ni], acc[mi][ni]);
      __builtin_amdgcn_s_setprio(0);
    }
    if (i < 15) {
      asm volatile("s_waitcnt vmcnt(0)" ::: "memory");   // tile i+1 landed
      __builtin_amdgcn_s_barrier();
      asm volatile("" ::: "memory");
    }
  }

  const float* bp = (bn < 1024) ? b0 : ((bn < 2048) ? b1 : b2);
#pragma unroll
  for (int ni = 0; ni < 4; ni++) {
    int col = bn + wn + ni * 16 + l16;
    float bias = bp[col & 1023];
#pragma unroll
    for (int mi = 0; mi < 4; mi++)
#pragma unroll
      for (int r = 0; r < 4; r++) {
        int row = bm + wm + mi * 16 + quad * 4 + r;
        float v = acc[mi][ni][r] + bias;
        if (OUTF32)
          reinterpret_cast<float*>(Cv)[(size_t)row * ldc + col] = v;
        else
          reinterpret_cast<u16*>(Cv)[(size_t)row * ldc + col] = f2bf(v);
      }
  }
}

// ---------------- V transpose: vt[bh][d][t] ----------------
__global__ __launch_bounds__(256) void vtrans(const u16* __restrict__ qkv,
                                              u16* __restrict__ vt) {
  const int tb = blockIdx.x;
  const int bh = blockIdx.y;
  const int b = bh >> 4, h = bh & 15;
  __shared__ u16 Vl[64][72];
  const int tid = threadIdx.x;
#pragma unroll
  for (int it = 0; it < 2; it++) {
    int c = it * 256 + tid;
    int t = c >> 3, dc = (c & 7) * 8;
    u16x8 v = *reinterpret_cast<const u16x8*>(
        qkv + (size_t)(b * T_ + tb * 64 + t) * 3072 + 2048 + h * 64 + dc);
    *reinterpret_cast<u16x8*>(&Vl[t][dc]) = v;
  }
  __syncthreads();
#pragma unroll
  for (int it = 0; it < 2; it++) {
    int c = it * 256 + tid;
    int d = c >> 3, tt = (c & 7) * 8;
    u16x8 o;
#pragma unroll
    for (int j = 0; j < 8; j++) o[j] = Vl[tt + j][d];
    *reinterpret_cast<u16x8*>(vt + ((size_t)bh * 64 + d) * T_ + tb * 64 + tt) = o;
  }
}

// ---------------- LSR projection via MFMA ----------------
__global__ __launch_bounds__(256) void lsr_mfma(const u16* __restrict__ qkv,
                                                const float* __restrict__ Wql,
                                                const float* __restrict__ Wkl,
                                                u16* __restrict__ qlr,
                                                u16* __restrict__ klr) {
  const int t0 = blockIdx.x * 128;
  const int bh = blockIdx.y, b = bh >> 4, h = bh & 15;
  const int sel = blockIdx.z;
  const int tid = threadIdx.x, lane = tid & 63, w = tid >> 6;
  const int quad = lane >> 4, l16 = lane & 15;
  __shared__ __align__(16) u16 Al[128 * 64];
  __shared__ __align__(16) u16 Wl[32 * 72];

  const float* Wsrc = (sel ? Wkl : Wql) + h * 2048;
  const float fold = sel ? 1.0f : 0.25506100790944405f;  // (1/sqrt(32))*log2(e)
  {
    float4 a = *reinterpret_cast<const float4*>(Wsrc + tid * 8);
    float4 c = *reinterpret_cast<const float4*>(Wsrc + tid * 8 + 4);
    float vals[8] = {a.x, a.y, a.z, a.w, c.x, c.y, c.z, c.w};
#pragma unroll
    for (int i = 0; i < 8; i++) {
      int idx = tid * 8 + i, d = idx >> 5, r = idx & 31;
      Wl[r * 72 + d] = f2bf(vals[i] * fold);
    }
  }
#pragma unroll
  for (int issue = 0; issue < 4; issue++) {
    int l = issue * 256 + tid;
    int t = l >> 3, ck = l & 7;
    const u16* src = qkv + (size_t)(b * T_ + t0 + t) * 3072 + sel * 1024 + h * 64 +
                     ((ck ^ (t & 7)) * 8);
    async_copy16(src, Al + issue * 2048 + w * 512);
  }
  __syncthreads();

  bf16x8 wf[2][2], af[2][2];
#pragma unroll
  for (int mr = 0; mr < 2; mr++)
#pragma unroll
    for (int c = 0; c < 2; c++)
      wf[mr][c] = *reinterpret_cast<const bf16x8*>(&Wl[(mr * 16 + l16) * 72 + c * 32 + quad * 8]);
#pragma unroll
  for (int i = 0; i < 2; i++) {
    int t = (2 * w + i) * 16 + l16;
#pragma unroll
    for (int c = 0; c < 2; c++)
      af[i][c] = *reinterpret_cast<const bf16x8*>(&Al[t * 64 + (((4 * c + quad) ^ (t & 7)) * 8)]);
  }
  floatx4 acc[2][2];
#pragma unroll
  for (int i = 0; i < 2; i++)
#pragma unroll
    for (int mr = 0; mr < 2; mr++) acc[i][mr] = (floatx4){0.f, 0.f, 0.f, 0.f};
#pragma unroll
  for (int i = 0; i < 2; i++)
#pragma unroll
    for (int mr = 0; mr < 2; mr++)
#pragma unroll
      for (int c = 0; c < 2; c++)
        acc[i][mr] = MFMA16(wf[mr][c], af[i][c], acc[i][mr]);

  u16* outp = sel ? klr : qlr;
#pragma unroll
  for (int i = 0; i < 2; i++) {
    int t = t0 + (2 * w + i) * 16 + l16;
#pragma unroll
    for (int mr = 0; mr < 2; mr++) {
      uint2 pv = { pack_bf(acc[i][mr][0], acc[i][mr][1]),
                   pack_bf(acc[i][mr][2], acc[i][mr][3]) };
      *reinterpret_cast<uint2*>(outp + ((size_t)bh * T_ + t) * 32 + mr * 16 + quad * 4) = pv;
    }
  }
}

// ---------------- flash attention, S^T orientation, register-resident P ----------------
__global__ __launch_bounds__(256, 4) void attn(const u16* __restrict__ qlr,
                                               const u16* __restrict__ klr,
                                               const u16* __restrict__ vt,
                                               u16* __restrict__ yatt) {
  const int bh = blockIdx.y;
  const int b = bh >> 4, h = bh & 15;
  const int p = blockIdx.x;                       // pair index 0..15
  const int tid = threadIdx.x, lane = tid & 63, w = tid >> 6;
  const int quad = lane >> 4, l16 = lane & 15;

  __shared__ __align__(16) u16 Vt3[3][4096];      // 24 KB: V^T tiles [d=64][64 keys]
  __shared__ __align__(16) u16 Kt3[3][2048];      // 12 KB: K tiles   [64 keys][32 rk]

  const u16* qlr_bh = qlr + (size_t)bh * T_ * RK_;
  const u16* klr_bh = klr + (size_t)bh * T_ * RK_;
  const u16* vt_bh  = vt + (size_t)bh * 64 * T_;

  // hoisted V LDS read offsets: A-frag (nt,dt): d=dt*16+l16, keys nt*16+quad*4..+3
  int voff[4][4];
#pragma unroll
  for (int nt = 0; nt < 4; nt++)
#pragma unroll
    for (int dt = 0; dt < 4; dt++) {
      int d = dt * 16 + l16;
      voff[nt][dt] = d * 64 + (((nt * 2 + (quad >> 1)) ^ (d & 7)) * 8) + (quad & 1) * 4;
    }
  // V staging source offsets (pre-swizzled so linear LDS dest ends up swizzled)
  int soffV[2];
#pragma unroll
  for (int issue = 0; issue < 2; issue++) {
    int L = issue * 256 + tid;
    int d = L >> 3, cg = L & 7;
    soffV[issue] = d * T_ + ((cg ^ (d & 7)) * 8);
  }
  // K staging: 32 pair-rows (2 keys = 128B) x 8 slots of 16B, slot s <- src slot s^(pr&7)
  const int soffK = (w * 8 + (lane >> 3)) * 64 + (((lane & 7) ^ (lane >> 3)) * 8);
  // K read: key k=nt*16+l16, rk slot quad -> koff + nt*512
  const int koff = (l16 >> 1) * 64 + ((((l16 & 1) * 4 + quad) ^ (l16 >> 1)) * 8);
  const int wub = w * 512;

  const floatx4 fzero = {0.f, 0.f, 0.f, 0.f};

  for (int run = 0; run < 2; run++) {
    const int qi = run ? p : 31 - p;              // heavy q-tile first
    const int q0 = qi * 64;
    if (run) __syncthreads();                     // WAR fence before restaging buf0/1

    bf16x8 qf = *reinterpret_cast<const bf16x8*>(
        qlr_bh + (size_t)(q0 + w * 16 + l16) * 32 + quad * 8);

    auto stage = [&](int t, int bi) {             // 3 vmcnt ops per wave
      const u16* vs = vt_bh + t * 64;
      async_copy16(vs + soffV[0], &Vt3[bi][wub]);
      async_copy16(vs + soffV[1], &Vt3[bi][2048 + wub]);
      async_copy16(klr_bh + t * 2048 + soffK, &Kt3[bi][wub]);
    };

    stage(0, 0);
    if (qi >= 1) {
      stage(1, 1);
      asm volatile("s_waitcnt vmcnt(3)" ::: "memory");   // stage(0) landed
    } else {
      asm volatile("s_waitcnt vmcnt(0)" ::: "memory");
    }
    __builtin_amdgcn_s_barrier();
    asm volatile("" ::: "memory");                // no LDS reads hoist above barrier

    floatx4 oacc[4];
#pragma unroll
    for (int i = 0; i < 4; i++) oacc[i] = fzero;
    float rs = 0.f;

    const u16* Vb = &Vt3[0][0];
    const u16* Kb = &Kt3[0][0];
    int cb = 0, sb = 2;

    // ---- full tiles ----
    for (int i = 0; i < qi; i++) {
      const bool do_stage = (i + 2 <= qi);
      if (do_stage) stage(i + 2, sb);

      bf16x8 kf[4];
#pragma unroll
      for (int nt = 0; nt < 4; nt++)
        kf[nt] = *reinterpret_cast<const bf16x8*>(Kb + koff + nt * 512);
      floatx4 sv[4];
#pragma unroll
      for (int nt = 0; nt < 4; nt++) sv[nt] = MFMA16(kf[nt], qf, fzero);

      uint2 pk[4];
#pragma unroll
      for (int nt = 0; nt < 4; nt++) {
        float p0 = __builtin_amdgcn_exp2f(sv[nt][0]);
        float p1 = __builtin_amdgcn_exp2f(sv[nt][1]);
        float p2 = __builtin_amdgcn_exp2f(sv[nt][2]);
        float p3 = __builtin_amdgcn_exp2f(sv[nt][3]);
        rs += (p0 + p1) + (p2 + p3);
        pk[nt].x = tpack(p0, p1);
        pk[nt].y = tpack(p2, p3);
      }
#pragma unroll
      for (int dt = 0; dt < 4; dt++)
#pragma unroll
        for (int nt = 0; nt < 4; nt++) {
          s16x4 vf = *reinterpret_cast<const s16x4*>(Vb + voff[nt][dt]);
          oacc[dt] = MFMA1K(vf, __builtin_bit_cast(s16x4, pk[nt]), oacc[dt]);
        }

      // counted wait: stage(i+2) may stay in flight; stage(i+1) is done
      if (do_stage) asm volatile("s_waitcnt vmcnt(3)" ::: "memory");
      else          asm volatile("s_waitcnt vmcnt(0)" ::: "memory");
      __builtin_amdgcn_s_barrier();
      asm volatile("" ::: "memory");

      cb = (cb == 2) ? 0 : cb + 1;
      Vb = &Vt3[cb][0];
      Kb = &Kt3[cb][0];
      if (do_stage) sb = (sb == 2) ? 0 : sb + 1;
    }

    // ---- diagonal tile (masked) ----
    {
      bf16x8 kf[4];
#pragma unroll
      for (int nt = 0; nt < 4; nt++)
        kf[nt] = *reinterpret_cast<const bf16x8*>(Kb + koff + nt * 512);
      floatx4 sv[4];
#pragma unroll
      for (int nt = 0; nt < 4; nt++) sv[nt] = MFMA16(kf[nt], qf, fzero);
      const int thr = w * 16 + l16;
      uint2 pk[4];
#pragma unroll
      for (int nt = 0; nt < 4; nt++) {
        float pr[4];
#pragma unroll
        for (int r = 0; r < 4; r++) {
          float e = __builtin_amdgcn_exp2f(sv[nt][r]);
          pr[r] = (nt * 16 + quad * 4 + r <= thr) ? e : 0.f;
        }
        rs += (pr[0] + pr[1]) + (pr[2] + pr[3]);
        pk[nt].x = tpack(pr[0], pr[1]);
        pk[nt].y = tpack(pr[2], pr[3]);
      }
#pragma unroll
      for (int dt = 0; dt < 4; dt++)
#pragma unroll
        for (int nt = 0; nt < 4; nt++) {
          s16x4 vf = *reinterpret_cast<const s16x4*>(Vb + voff[nt][dt]);
          oacc[dt] = MFMA1K(vf, __builtin_bit_cast(s16x4, pk[nt]), oacc[dt]);
        }
    }

    // row-sum across the 4 quads; normalize; store O^T (d = dt*16+quad*4+r, qrow = l16)
    rs += __shfl_xor(rs, 16);
    rs += __shfl_xor(rs, 32);
    float inv = 1.f / rs;
    const int qrow = q0 + w * 16 + l16;
#pragma unroll
    for (int dt = 0; dt < 4; dt++) {
      uint2 ov = { pack_bf(oacc[dt][0] * inv, oacc[dt][1] * inv),
                   pack_bf(oacc[dt][2] * inv, oacc[dt][3] * inv) };
      *reinterpret_cast<uint2*>(
          yatt + (size_t)(b * T_ + qrow) * 1024 + h * 64 + dt * 16 + quad * 4) = ov;
    }
  }
}

// ---------------- launch ----------------
extern "C" void kernel_launch(void* const* d_in, const int* in_sizes, int n_in,
                              void* d_out, int out_size, void* d_ws, size_t ws_size,
                              hipStream_t stream) {
  const float* x   = (const float*)d_in[0];
  const float* Wq  = (const float*)d_in[1];
  const float* bq  = (const float*)d_in[2];
  const float* Wk  = (const float*)d_in[3];
  const float* bk  = (const float*)d_in[4];
  const float* Wv  = (const float*)d_in[5];
  const float* bv  = (const float*)d_in[6];
  const float* Wo  = (const float*)d_in[7];
  const float* bo  = (const float*)d_in[8];
  const float* Wql = (const float*)d_in[9];
  const float* Wkl = (const float*)d_in[10];
  float* out = (float*)d_out;

  char* ws = (char*)d_ws;
  u16* xb   = (u16*)(ws);                    // 8192x1024 bf16 (16 MB) -- reused as vt
  u16* Wcat = (u16*)(ws + 16777216);         // 4096x1024 bf16 (8 MB)
  u16* qkv  = (u16*)(ws + 25165824);         // 8192x3072 bf16 (50 MB)
  u16* qlr  = (u16*)(ws + 75497472);         // 64x2048x32 bf16 (8 MB)
  u16* klr  = (u16*)(ws + 83886080);         // 64x2048x32 bf16 (8 MB)
  u16* yatt = (u16*)(ws + 92274688);         // 8192x1024 bf16 (16 MB)
  u16* vt   = xb;                            // [bh][64][2048] bf16, after gemm0

  cvt_x<<<dim3(8192), 256, 0, stream>>>(x, xb, 2097152);
  cvt_weights<<<dim3(4096), 256, 0, stream>>>(Wq, Wk, Wv, Wo, Wcat);
  gemm8<0><<<dim3(1536), 256, 0, stream>>>(xb, Wcat, bq, bk, bv, qkv, 3072);
  vtrans<<<dim3(32, 64), 256, 0, stream>>>(qkv, vt);
  lsr_mfma<<<dim3(16, 64, 2), 256, 0, stream>>>(qkv, Wql, Wkl, qlr, klr);
  attn<<<dim3(16, 64), 256, 0, stream>>>(qlr, klr, vt, yatt);
  gemm8<1><<<dim3(512), 256, 0, stream>>>(yatt, Wcat + 3145728, bo, bo, bo, out, 1024);
}

// Round 3
// 253.264 us; speedup vs baseline: 1.1721x; 1.0693x over previous
//
#include <hip/hip_runtime.h>

#define B_  4
#define T_  2048
#define H_  16
#define DM_ 1024
#define DH_ 64
#define RK_ 32

using u16 = unsigned short;
using u32 = unsigned int;
typedef float  floatx4 __attribute__((ext_vector_type(4)));
typedef __bf16 bf16x8  __attribute__((ext_vector_type(8)));
typedef u16    u16x8   __attribute__((ext_vector_type(8)));
typedef u16    u16x4   __attribute__((ext_vector_type(4)));
typedef short  s16x4   __attribute__((ext_vector_type(4)));

#define MFMA16(a,b,c) __builtin_amdgcn_mfma_f32_16x16x32_bf16((a),(b),(c),0,0,0)
// K=16 bf16 MFMA: A/B frag = 4 bf16 (k = quad*4+j), C/D same 16x16 layout
#define MFMA1K(a,b,c) __builtin_amdgcn_mfma_f32_16x16x16bf16_1k((a),(b),(c),0,0,0)

__device__ __forceinline__ u16 f2bf(float f) {
  unsigned u = __float_as_uint(f);
  u += 0x7fffu + ((u >> 16) & 1u);   // RNE
  return (u16)(u >> 16);
}
__device__ __forceinline__ float b2f(u16 h) {
  return __uint_as_float(((unsigned)h) << 16);
}
// RNE pack: (bf16(b)<<16)|bf16(a)
__device__ __forceinline__ u32 pack_bf(float a, float b) {
  u32 ua = __float_as_uint(a); ua += 0x7fffu + ((ua >> 16) & 1u);
  u32 ub = __float_as_uint(b); ub += 0x7fffu + ((ub >> 16) & 1u);
  return __builtin_amdgcn_perm(ub, ua, 0x07060302u);
}
// truncation pack (1 instr) — for P in the hot loop (values > 0)
__device__ __forceinline__ u32 tpack(float a, float b) {
  return __builtin_amdgcn_perm(__float_as_uint(b), __float_as_uint(a), 0x07060302u);
}

// async global->LDS, 16B per lane. LDS dest is wave-uniform base; HW adds lane*16.
__device__ __forceinline__ void async_copy16(const u16* g, const u16* lds_uniform_base) {
  __builtin_amdgcn_global_load_lds(
      (const __attribute__((address_space(1))) unsigned int*)(unsigned long long)g,
      (__attribute__((address_space(3))) unsigned int*)(unsigned int)(unsigned long long)lds_uniform_base,
      16, 0, 0);
}

// ---------------- conversion kernels ----------------
__global__ __launch_bounds__(256) void cvt_x(const float* __restrict__ s,
                                             u16* __restrict__ d, int n4) {
  int i = blockIdx.x * 256 + threadIdx.x;
  if (i >= n4) return;
  float4 v = reinterpret_cast<const float4*>(s)[i];
  u16x4 o = { f2bf(v.x), f2bf(v.y), f2bf(v.z), f2bf(v.w) };
  reinterpret_cast<u16x4*>(d)[i] = o;
}

__global__ __launch_bounds__(256) void cvt_weights(const float* __restrict__ Wq,
                                                   const float* __restrict__ Wk,
                                                   const float* __restrict__ Wv,
                                                   const float* __restrict__ Wo,
                                                   u16* __restrict__ Wcat) {
  int i = blockIdx.x * 256 + threadIdx.x;
  int reg = i >> 18;
  const float* s = (reg == 0) ? Wq : (reg == 1) ? Wk : (reg == 2) ? Wv : Wo;
  int j = i & 262143;
  float4 v = reinterpret_cast<const float4*>(s)[j];
  u16x4 o = { f2bf(v.x), f2bf(v.y), f2bf(v.z), f2bf(v.w) };
  reinterpret_cast<u16x4*>(Wcat)[i] = o;
}

// ---------------- GEMM v3: C[M,N] = A[M,K] * W[N,K]^T + bias, K=1024 ----------------
// 128x128 tile, BK=64, double-buffered 64KB LDS with XOR-swizzle (slot ^= row&7, T2):
// conflict-free ds_read_b128 (verified: SQ_LDS_BANK_CONFLICT = 0 in round 2).
// Stage via global_load_lds with PRE-SWIZZLED global source (linear LDS dest, rule #21).
// v3: plain 2D grid, default dispatch order (round-robin XCD on consecutive bm blocks)
// — each XCD's L2 holds ~2MB of A rows + the ~8 live W panels; A swept ~once per
// 8-panel residency phase. Round-2's contiguous-chunk XCD swizzle caused 5x A
// re-fetch (FETCH 41->200 MB); this reverts exactly that, keeping the LDS wins.
template <int OUTF32>
__global__ __launch_bounds__(256, 2) void gemm8(const u16* __restrict__ A,
                                                const u16* __restrict__ W,
                                                const float* __restrict__ b0,
                                                const float* __restrict__ b1,
                                                const float* __restrict__ b2,
                                                void* __restrict__ Cv, int ldc) {
  __shared__ __align__(16) u16 Al[2][8192];   // [buf][128 rows][64 k] swizzled
  __shared__ __align__(16) u16 Bl[2][8192];
  const int tid  = threadIdx.x;
  const int lane = tid & 63;
  const int w    = tid >> 6;
  const int quad = lane >> 4;
  const int l16  = lane & 15;
  const int wm   = (w >> 1) << 6;
  const int wn   = (w & 1) << 6;

  const int bm = blockIdx.x << 7;
  const int bn = blockIdx.y << 7;

  // staging: thread tid covers LDS row (chunk*32 + tid>>3), slot tid&7.
  // source k-slot pre-swizzled so LDS slot s holds source slot s^(row&7).
  const int sr = tid >> 3;
  const int sc = ((tid & 7) ^ (sr & 7)) * 8;
  const u16* Ag = A + (size_t)(bm + sr) * 1024 + sc;
  const u16* Wg = W + (size_t)(bn + sr) * 1024 + sc;

  auto stage = [&](int k0, int bsel) {        // 8 vm ops / tile
#pragma unroll
    for (int j = 0; j < 4; j++)
      async_copy16(Ag + (size_t)j * 32768 + k0, &Al[bsel][j * 2048 + w * 512]);
#pragma unroll
    for (int j = 0; j < 4; j++)
      async_copy16(Wg + (size_t)j * 32768 + k0, &Bl[bsel][j * 2048 + w * 512]);
  };

  // fragment read offsets (u16): row*64 + ((ks*4+quad)^(row&7))*8, row&7 == l16&7
  int aoff[4], boff[4], sl[2];
#pragma unroll
  for (int mi = 0; mi < 4; mi++) aoff[mi] = (wm + mi * 16 + l16) * 64;
#pragma unroll
  for (int ni = 0; ni < 4; ni++) boff[ni] = (wn + ni * 16 + l16) * 64;
  sl[0] = ((0 + quad) ^ (l16 & 7)) * 8;
  sl[1] = ((4 + quad) ^ (l16 & 7)) * 8;

  floatx4 acc[4][4];
#pragma unroll
  for (int i = 0; i < 4; i++)
#pragma unroll
    for (int j = 0; j < 4; j++) acc[i][j] = (floatx4){0.f, 0.f, 0.f, 0.f};

  stage(0, 0);
  asm volatile("s_waitcnt vmcnt(0)" ::: "memory");
  __builtin_amdgcn_s_barrier();
  asm volatile("" ::: "memory");

  for (int i = 0; i < 16; i++) {
    if (i < 15) stage((i + 1) * 64, (i + 1) & 1);
    const u16* Ab = Al[i & 1];
    const u16* Bb = Bl[i & 1];
#pragma unroll
    for (int ks = 0; ks < 2; ks++) {
      bf16x8 af[4], bfr[4];
#pragma unroll
      for (int mi = 0; mi < 4; mi++)
        af[mi] = *reinterpret_cast<const bf16x8*>(Ab + aoff[mi] + sl[ks]);
#pragma unroll
      for (int ni = 0; ni < 4; ni++)
        bfr[ni] = *reinterpret_cast<const bf16x8*>(Bb + boff[ni] + sl[ks]);
      __builtin_amdgcn_s_setprio(1);
#pragma unroll
      for (int mi = 0; mi < 4; mi++)
#pragma unroll
        for (int ni = 0; ni < 4; ni++)
          acc[mi][ni] = MFMA16(af[mi], bfr[ni], acc[mi][ni]);
      __builtin_amdgcn_s_setprio(0);
    }
    if (i < 15) {
      asm volatile("s_waitcnt vmcnt(0)" ::: "memory");   // tile i+1 landed
      __builtin_amdgcn_s_barrier();
      asm volatile("" ::: "memory");
    }
  }

  const float* bp = (bn < 1024) ? b0 : ((bn < 2048) ? b1 : b2);
#pragma unroll
  for (int ni = 0; ni < 4; ni++) {
    int col = bn + wn + ni * 16 + l16;
    float bias = bp[col & 1023];
#pragma unroll
    for (int mi = 0; mi < 4; mi++)
#pragma unroll
      for (int r = 0; r < 4; r++) {
        int row = bm + wm + mi * 16 + quad * 4 + r;
        float v = acc[mi][ni][r] + bias;
        if (OUTF32)
          reinterpret_cast<float*>(Cv)[(size_t)row * ldc + col] = v;
        else
          reinterpret_cast<u16*>(Cv)[(size_t)row * ldc + col] = f2bf(v);
      }
  }
}

// ---------------- V transpose: vt[bh][d][t] ----------------
__global__ __launch_bounds__(256) void vtrans(const u16* __restrict__ qkv,
                                              u16* __restrict__ vt) {
  const int tb = blockIdx.x;
  const int bh = blockIdx.y;
  const int b = bh >> 4, h = bh & 15;
  __shared__ u16 Vl[64][72];
  const int tid = threadIdx.x;
#pragma unroll
  for (int it = 0; it < 2; it++) {
    int c = it * 256 + tid;
    int t = c >> 3, dc = (c & 7) * 8;
    u16x8 v = *reinterpret_cast<const u16x8*>(
        qkv + (size_t)(b * T_ + tb * 64 + t) * 3072 + 2048 + h * 64 + dc);
    *reinterpret_cast<u16x8*>(&Vl[t][dc]) = v;
  }
  __syncthreads();
#pragma unroll
  for (int it = 0; it < 2; it++) {
    int c = it * 256 + tid;
    int d = c >> 3, tt = (c & 7) * 8;
    u16x8 o;
#pragma unroll
    for (int j = 0; j < 8; j++) o[j] = Vl[tt + j][d];
    *reinterpret_cast<u16x8*>(vt + ((size_t)bh * 64 + d) * T_ + tb * 64 + tt) = o;
  }
}

// ---------------- LSR projection via MFMA ----------------
__global__ __launch_bounds__(256) void lsr_mfma(const u16* __restrict__ qkv,
                                                const float* __restrict__ Wql,
                                                const float* __restrict__ Wkl,
                                                u16* __restrict__ qlr,
                                                u16* __restrict__ klr) {
  const int t0 = blockIdx.x * 128;
  const int bh = blockIdx.y, b = bh >> 4, h = bh & 15;
  const int sel = blockIdx.z;
  const int tid = threadIdx.x, lane = tid & 63, w = tid >> 6;
  const int quad = lane >> 4, l16 = lane & 15;
  __shared__ __align__(16) u16 Al[128 * 64];
  __shared__ __align__(16) u16 Wl[32 * 72];

  const float* Wsrc = (sel ? Wkl : Wql) + h * 2048;
  const float fold = sel ? 1.0f : 0.25506100790944405f;  // (1/sqrt(32))*log2(e)
  {
    float4 a = *reinterpret_cast<const float4*>(Wsrc + tid * 8);
    float4 c = *reinterpret_cast<const float4*>(Wsrc + tid * 8 + 4);
    float vals[8] = {a.x, a.y, a.z, a.w, c.x, c.y, c.z, c.w};
#pragma unroll
    for (int i = 0; i < 8; i++) {
      int idx = tid * 8 + i, d = idx >> 5, r = idx & 31;
      Wl[r * 72 + d] = f2bf(vals[i] * fold);
    }
  }
#pragma unroll
  for (int issue = 0; issue < 4; issue++) {
    int l = issue * 256 + tid;
    int t = l >> 3, ck = l & 7;
    const u16* src = qkv + (size_t)(b * T_ + t0 + t) * 3072 + sel * 1024 + h * 64 +
                     ((ck ^ (t & 7)) * 8);
    async_copy16(src, Al + issue * 2048 + w * 512);
  }
  __syncthreads();

  bf16x8 wf[2][2], af[2][2];
#pragma unroll
  for (int mr = 0; mr < 2; mr++)
#pragma unroll
    for (int c = 0; c < 2; c++)
      wf[mr][c] = *reinterpret_cast<const bf16x8*>(&Wl[(mr * 16 + l16) * 72 + c * 32 + quad * 8]);
#pragma unroll
  for (int i = 0; i < 2; i++) {
    int t = (2 * w + i) * 16 + l16;
#pragma unroll
    for (int c = 0; c < 2; c++)
      af[i][c] = *reinterpret_cast<const bf16x8*>(&Al[t * 64 + (((4 * c + quad) ^ (t & 7)) * 8)]);
  }
  floatx4 acc[2][2];
#pragma unroll
  for (int i = 0; i < 2; i++)
#pragma unroll
    for (int mr = 0; mr < 2; mr++) acc[i][mr] = (floatx4){0.f, 0.f, 0.f, 0.f};
#pragma unroll
  for (int i = 0; i < 2; i++)
#pragma unroll
    for (int mr = 0; mr < 2; mr++)
#pragma unroll
      for (int c = 0; c < 2; c++)
        acc[i][mr] = MFMA16(wf[mr][c], af[i][c], acc[i][mr]);

  u16* outp = sel ? klr : qlr;
#pragma unroll
  for (int i = 0; i < 2; i++) {
    int t = t0 + (2 * w + i) * 16 + l16;
#pragma unroll
    for (int mr = 0; mr < 2; mr++) {
      uint2 pv = { pack_bf(acc[i][mr][0], acc[i][mr][1]),
                   pack_bf(acc[i][mr][2], acc[i][mr][3]) };
      *reinterpret_cast<uint2*>(outp + ((size_t)bh * T_ + t) * 32 + mr * 16 + quad * 4) = pv;
    }
  }
}

// ---------------- flash attention, S^T orientation, register-resident P ----------------
__global__ __launch_bounds__(256, 4) void attn(const u16* __restrict__ qlr,
                                               const u16* __restrict__ klr,
                                               const u16* __restrict__ vt,
                                               u16* __restrict__ yatt) {
  const int bh = blockIdx.y;
  const int b = bh >> 4, h = bh & 15;
  const int p = blockIdx.x;                       // pair index 0..15
  const int tid = threadIdx.x, lane = tid & 63, w = tid >> 6;
  const int quad = lane >> 4, l16 = lane & 15;

  __shared__ __align__(16) u16 Vt3[3][4096];      // 24 KB: V^T tiles [d=64][64 keys]
  __shared__ __align__(16) u16 Kt3[3][2048];      // 12 KB: K tiles   [64 keys][32 rk]

  const u16* qlr_bh = qlr + (size_t)bh * T_ * RK_;
  const u16* klr_bh = klr + (size_t)bh * T_ * RK_;
  const u16* vt_bh  = vt + (size_t)bh * 64 * T_;

  // hoisted V LDS read offsets: A-frag (nt,dt): d=dt*16+l16, keys nt*16+quad*4..+3
  int voff[4][4];
#pragma unroll
  for (int nt = 0; nt < 4; nt++)
#pragma unroll
    for (int dt = 0; dt < 4; dt++) {
      int d = dt * 16 + l16;
      voff[nt][dt] = d * 64 + (((nt * 2 + (quad >> 1)) ^ (d & 7)) * 8) + (quad & 1) * 4;
    }
  // V staging source offsets (pre-swizzled so linear LDS dest ends up swizzled)
  int soffV[2];
#pragma unroll
  for (int issue = 0; issue < 2; issue++) {
    int L = issue * 256 + tid;
    int d = L >> 3, cg = L & 7;
    soffV[issue] = d * T_ + ((cg ^ (d & 7)) * 8);
  }
  // K staging: 32 pair-rows (2 keys = 128B) x 8 slots of 16B, slot s <- src slot s^(pr&7)
  const int soffK = (w * 8 + (lane >> 3)) * 64 + (((lane & 7) ^ (lane >> 3)) * 8);
  // K read: key k=nt*16+l16, rk slot quad -> koff + nt*512
  const int koff = (l16 >> 1) * 64 + ((((l16 & 1) * 4 + quad) ^ (l16 >> 1)) * 8);
  const int wub = w * 512;

  const floatx4 fzero = {0.f, 0.f, 0.f, 0.f};

  for (int run = 0; run < 2; run++) {
    const int qi = run ? p : 31 - p;              // heavy q-tile first
    const int q0 = qi * 64;
    if (run) __syncthreads();                     // WAR fence before restaging buf0/1

    bf16x8 qf = *reinterpret_cast<const bf16x8*>(
        qlr_bh + (size_t)(q0 + w * 16 + l16) * 32 + quad * 8);

    auto stage = [&](int t, int bi) {             // 3 vmcnt ops per wave
      const u16* vs = vt_bh + t * 64;
      async_copy16(vs + soffV[0], &Vt3[bi][wub]);
      async_copy16(vs + soffV[1], &Vt3[bi][2048 + wub]);
      async_copy16(klr_bh + t * 2048 + soffK, &Kt3[bi][wub]);
    };

    stage(0, 0);
    if (qi >= 1) {
      stage(1, 1);
      asm volatile("s_waitcnt vmcnt(3)" ::: "memory");   // stage(0) landed
    } else {
      asm volatile("s_waitcnt vmcnt(0)" ::: "memory");
    }
    __builtin_amdgcn_s_barrier();
    asm volatile("" ::: "memory");                // no LDS reads hoist above barrier

    floatx4 oacc[4];
#pragma unroll
    for (int i = 0; i < 4; i++) oacc[i] = fzero;
    float rs = 0.f;

    const u16* Vb = &Vt3[0][0];
    const u16* Kb = &Kt3[0][0];
    int cb = 0, sb = 2;

    // ---- full tiles ----
    for (int i = 0; i < qi; i++) {
      const bool do_stage = (i + 2 <= qi);
      if (do_stage) stage(i + 2, sb);

      bf16x8 kf[4];
#pragma unroll
      for (int nt = 0; nt < 4; nt++)
        kf[nt] = *reinterpret_cast<const bf16x8*>(Kb + koff + nt * 512);
      floatx4 sv[4];
#pragma unroll
      for (int nt = 0; nt < 4; nt++) sv[nt] = MFMA16(kf[nt], qf, fzero);

      uint2 pk[4];
#pragma unroll
      for (int nt = 0; nt < 4; nt++) {
        float p0 = __builtin_amdgcn_exp2f(sv[nt][0]);
        float p1 = __builtin_amdgcn_exp2f(sv[nt][1]);
        float p2 = __builtin_amdgcn_exp2f(sv[nt][2]);
        float p3 = __builtin_amdgcn_exp2f(sv[nt][3]);
        rs += (p0 + p1) + (p2 + p3);
        pk[nt].x = tpack(p0, p1);
        pk[nt].y = tpack(p2, p3);
      }
#pragma unroll
      for (int dt = 0; dt < 4; dt++)
#pragma unroll
        for (int nt = 0; nt < 4; nt++) {
          s16x4 vf = *reinterpret_cast<const s16x4*>(Vb + voff[nt][dt]);
          oacc[dt] = MFMA1K(vf, __builtin_bit_cast(s16x4, pk[nt]), oacc[dt]);
        }

      // counted wait: stage(i+2) may stay in flight; stage(i+1) is done
      if (do_stage) asm volatile("s_waitcnt vmcnt(3)" ::: "memory");
      else          asm volatile("s_waitcnt vmcnt(0)" ::: "memory");
      __builtin_amdgcn_s_barrier();
      asm volatile("" ::: "memory");

      cb = (cb == 2) ? 0 : cb + 1;
      Vb = &Vt3[cb][0];
      Kb = &Kt3[cb][0];
      if (do_stage) sb = (sb == 2) ? 0 : sb + 1;
    }

    // ---- diagonal tile (masked) ----
    {
      bf16x8 kf[4];
#pragma unroll
      for (int nt = 0; nt < 4; nt++)
        kf[nt] = *reinterpret_cast<const bf16x8*>(Kb + koff + nt * 512);
      floatx4 sv[4];
#pragma unroll
      for (int nt = 0; nt < 4; nt++) sv[nt] = MFMA16(kf[nt], qf, fzero);
      const int thr = w * 16 + l16;
      uint2 pk[4];
#pragma unroll
      for (int nt = 0; nt < 4; nt++) {
        float pr[4];
#pragma unroll
        for (int r = 0; r < 4; r++) {
          float e = __builtin_amdgcn_exp2f(sv[nt][r]);
          pr[r] = (nt * 16 + quad * 4 + r <= thr) ? e : 0.f;
        }
        rs += (pr[0] + pr[1]) + (pr[2] + pr[3]);
        pk[nt].x = tpack(pr[0], pr[1]);
        pk[nt].y = tpack(pr[2], pr[3]);
      }
#pragma unroll
      for (int dt = 0; dt < 4; dt++)
#pragma unroll
        for (int nt = 0; nt < 4; nt++) {
          s16x4 vf = *reinterpret_cast<const s16x4*>(Vb + voff[nt][dt]);
          oacc[dt] = MFMA1K(vf, __builtin_bit_cast(s16x4, pk[nt]), oacc[dt]);
        }
    }

    // row-sum across the 4 quads; normalize; store O^T (d = dt*16+quad*4+r, qrow = l16)
    rs += __shfl_xor(rs, 16);
    rs += __shfl_xor(rs, 32);
    float inv = 1.f / rs;
    const int qrow = q0 + w * 16 + l16;
#pragma unroll
    for (int dt = 0; dt < 4; dt++) {
      uint2 ov = { pack_bf(oacc[dt][0] * inv, oacc[dt][1] * inv),
                   pack_bf(oacc[dt][2] * inv, oacc[dt][3] * inv) };
      *reinterpret_cast<uint2*>(
          yatt + (size_t)(b * T_ + qrow) * 1024 + h * 64 + dt * 16 + quad * 4) = ov;
    }
  }
}

// ---------------- launch ----------------
extern "C" void kernel_launch(void* const* d_in, const int* in_sizes, int n_in,
                              void* d_out, int out_size, void* d_ws, size_t ws_size,
                              hipStream_t stream) {
  const float* x   = (const float*)d_in[0];
  const float* Wq  = (const float*)d_in[1];
  const float* bq  = (const float*)d_in[2];
  const float* Wk  = (const float*)d_in[3];
  const float* bk  = (const float*)d_in[4];
  const float* Wv  = (const float*)d_in[5];
  const float* bv  = (const float*)d_in[6];
  const float* Wo  = (const float*)d_in[7];
  const float* bo  = (const float*)d_in[8];
  const float* Wql = (const float*)d_in[9];
  const float* Wkl = (const float*)d_in[10];
  float* out = (float*)d_out;

  char* ws = (char*)d_ws;
  u16* xb   = (u16*)(ws);                    // 8192x1024 bf16 (16 MB) -- reused as vt
  u16* Wcat = (u16*)(ws + 16777216);         // 4096x1024 bf16 (8 MB)
  u16* qkv  = (u16*)(ws + 25165824);         // 8192x3072 bf16 (50 MB)
  u16* qlr  = (u16*)(ws + 75497472);         // 64x2048x32 bf16 (8 MB)
  u16* klr  = (u16*)(ws + 83886080);         // 64x2048x32 bf16 (8 MB)
  u16* yatt = (u16*)(ws + 92274688);         // 8192x1024 bf16 (16 MB)
  u16* vt   = xb;                            // [bh][64][2048] bf16, after gemm0

  cvt_x<<<dim3(8192), 256, 0, stream>>>(x, xb, 2097152);
  cvt_weights<<<dim3(4096), 256, 0, stream>>>(Wq, Wk, Wv, Wo, Wcat);
  gemm8<0><<<dim3(64, 24), 256, 0, stream>>>(xb, Wcat, bq, bk, bv, qkv, 3072);
  vtrans<<<dim3(32, 64), 256, 0, stream>>>(qkv, vt);
  lsr_mfma<<<dim3(16, 64, 2), 256, 0, stream>>>(qkv, Wql, Wkl, qlr, klr);
  attn<<<dim3(16, 64), 256, 0, stream>>>(qlr, klr, vt, yatt);
  gemm8<1><<<dim3(64, 8), 256, 0, stream>>>(yatt, Wcat + 3145728, bo, bo, bo, out, 1024);
}

// Round 4
// 241.289 us; speedup vs baseline: 1.2302x; 1.0496x over previous
//
#include <hip/hip_runtime.h>

#define B_  4
#define T_  2048
#define H_  16
#define DM_ 1024
#define DH_ 64
#define RK_ 32

using u16 = unsigned short;
using u32 = unsigned int;
typedef float  floatx4 __attribute__((ext_vector_type(4)));
typedef __bf16 bf16x8  __attribute__((ext_vector_type(8)));
typedef u16    u16x8   __attribute__((ext_vector_type(8)));
typedef u16    u16x4   __attribute__((ext_vector_type(4)));
typedef short  s16x4   __attribute__((ext_vector_type(4)));

#define MFMA16(a,b,c) __builtin_amdgcn_mfma_f32_16x16x32_bf16((a),(b),(c),0,0,0)
// K=16 bf16 MFMA: A/B frag = 4 bf16 (k = quad*4+j), C/D same 16x16 layout
#define MFMA1K(a,b,c) __builtin_amdgcn_mfma_f32_16x16x16bf16_1k((a),(b),(c),0,0,0)

__device__ __forceinline__ u16 f2bf(float f) {
  unsigned u = __float_as_uint(f);
  u += 0x7fffu + ((u >> 16) & 1u);   // RNE
  return (u16)(u >> 16);
}
// RNE pack: (bf16(b)<<16)|bf16(a)
__device__ __forceinline__ u32 pack_bf(float a, float b) {
  u32 ua = __float_as_uint(a); ua += 0x7fffu + ((ua >> 16) & 1u);
  u32 ub = __float_as_uint(b); ub += 0x7fffu + ((ub >> 16) & 1u);
  return __builtin_amdgcn_perm(ub, ua, 0x07060302u);
}
// truncation pack (1 instr) — for P in the hot loop (values > 0)
__device__ __forceinline__ u32 tpack(float a, float b) {
  return __builtin_amdgcn_perm(__float_as_uint(b), __float_as_uint(a), 0x07060302u);
}

// async global->LDS, 16B per lane. LDS dest is wave-uniform base; HW adds lane*16.
__device__ __forceinline__ void async_copy16(const u16* g, const u16* lds_uniform_base) {
  __builtin_amdgcn_global_load_lds(
      (const __attribute__((address_space(1))) unsigned int*)(unsigned long long)g,
      (__attribute__((address_space(3))) unsigned int*)(unsigned int)(unsigned long long)lds_uniform_base,
      16, 0, 0);
}

// ---------------- conversion kernels ----------------
__global__ __launch_bounds__(256) void cvt_x(const float* __restrict__ s,
                                             u16* __restrict__ d, int n4) {
  int i = blockIdx.x * 256 + threadIdx.x;
  if (i >= n4) return;
  float4 v = reinterpret_cast<const float4*>(s)[i];
  u16x4 o = { f2bf(v.x), f2bf(v.y), f2bf(v.z), f2bf(v.w) };
  reinterpret_cast<u16x4*>(d)[i] = o;
}

// Wv -> Wcat rows [0,1024); Wo -> Wcat rows [2048,3072)
__global__ __launch_bounds__(256) void cvt_wvo(const float* __restrict__ Wv,
                                               const float* __restrict__ Wo,
                                               u16* __restrict__ Wcat) {
  int i = blockIdx.x * 256 + threadIdx.x;       // 2 x 262144 float4-groups
  int reg = i >> 18;
  const float* s = reg ? Wo : Wv;
  int j = i & 262143;
  float4 v = reinterpret_cast<const float4*>(s)[j];
  u16x4 o = { f2bf(v.x), f2bf(v.y), f2bf(v.z), f2bf(v.w) };
  reinterpret_cast<u16x4*>(Wcat)[(reg ? 524288 : 0) + j] = o;
}

// ---------------- LSR weight folding ----------------
// Weff[hr][dm] = fold * sum_d lsr[h][d][r] * W[h*64+d][dm]   (bf16 out)
// beff[hr]    = fold * sum_d lsr[h][d][r] * bias[h*64+d]     (f32 out)
// => q_lr = x @ Weff^T + beff reproduces (x@W^T+b)@L exactly (up to rounding).
__global__ __launch_bounds__(256) void lsr_fold(const float* __restrict__ W,
                                                const float* __restrict__ bias,
                                                const float* __restrict__ lsr,
                                                float fold,
                                                u16* __restrict__ Weff,
                                                float* __restrict__ beff) {
  const int hr = blockIdx.x;                    // 0..511
  const int h = hr >> 5, r = hr & 31;
  const int tid = threadIdx.x;
  __shared__ float lw[64];
  if (tid < 64) lw[tid] = lsr[(size_t)(h * 64 + tid) * 32 + r] * fold;
  __syncthreads();
  float a0 = 0.f, a1 = 0.f, a2 = 0.f, a3 = 0.f;
  for (int d = 0; d < 64; d++) {
    float l = lw[d];
    float4 wv = *reinterpret_cast<const float4*>(W + (size_t)(h * 64 + d) * 1024 + tid * 4);
    a0 += l * wv.x; a1 += l * wv.y; a2 += l * wv.z; a3 += l * wv.w;
  }
  u16x4 o = { f2bf(a0), f2bf(a1), f2bf(a2), f2bf(a3) };
  reinterpret_cast<u16x4*>(Weff)[(size_t)hr * 256 + tid] = o;
  if (tid == 0) {
    float s = 0.f;
    for (int d = 0; d < 64; d++) s += lw[d] * bias[h * 64 + d];
    beff[hr] = s;
  }
}

// ---------------- GEMM: C[M,N] = A[M,K] * W[N,K]^T + bias, K=1024 ----------------
// 128x128 tile, BK=64, double-buffered 64KB LDS with XOR-swizzle (slot ^= row&7, T2):
// conflict-free ds_read_b128 (verified: SQ_LDS_BANK_CONFLICT = 0). Stage via
// global_load_lds with PRE-SWIZZLED global source (linear LDS dest, rule #21).
// Plain 2D grid (round-robin XCD on consecutive bm keeps A+W panels L2-resident;
// verified FETCH ~= ideal in round 3).
// MODE 1: f32 out to Cv (ldc), bias b0.
// MODE 2: fused QKV-LSR epilogue: cols [0,1024) -> V bf16 (Cv, ldc=1024, bias b0);
//         cols [1024,1536) -> qlr in attn layout (bias b1);
//         cols [1536,2048) -> klr in attn layout (bias b2).
template <int MODE>
__global__ __launch_bounds__(256, 2) void gemm8(const u16* __restrict__ A,
                                                const u16* __restrict__ W,
                                                const float* __restrict__ b0,
                                                const float* __restrict__ b1,
                                                const float* __restrict__ b2,
                                                void* __restrict__ Cv,
                                                u16* __restrict__ qo,
                                                u16* __restrict__ ko,
                                                int ldc) {
  __shared__ __align__(16) u16 Al[2][8192];   // [buf][128 rows][64 k] swizzled
  __shared__ __align__(16) u16 Bl[2][8192];
  const int tid  = threadIdx.x;
  const int lane = tid & 63;
  const int w    = tid >> 6;
  const int quad = lane >> 4;
  const int l16  = lane & 15;
  const int wm   = (w >> 1) << 6;
  const int wn   = (w & 1) << 6;

  const int bm = blockIdx.x << 7;
  const int bn = blockIdx.y << 7;

  // staging: thread tid covers LDS row (chunk*32 + tid>>3), slot tid&7.
  // source k-slot pre-swizzled so LDS slot s holds source slot s^(row&7).
  const int sr = tid >> 3;
  const int sc = ((tid & 7) ^ (sr & 7)) * 8;
  const u16* Ag = A + (size_t)(bm + sr) * 1024 + sc;
  const u16* Wg = W + (size_t)(bn + sr) * 1024 + sc;

  auto stage = [&](int k0, int bsel) {        // 8 vm ops / tile
#pragma unroll
    for (int j = 0; j < 4; j++)
      async_copy16(Ag + (size_t)j * 32768 + k0, &Al[bsel][j * 2048 + w * 512]);
#pragma unroll
    for (int j = 0; j < 4; j++)
      async_copy16(Wg + (size_t)j * 32768 + k0, &Bl[bsel][j * 2048 + w * 512]);
  };

  // fragment read offsets (u16): row*64 + ((ks*4+quad)^(row&7))*8, row&7 == l16&7
  int aoff[4], boff[4], sl[2];
#pragma unroll
  for (int mi = 0; mi < 4; mi++) aoff[mi] = (wm + mi * 16 + l16) * 64;
#pragma unroll
  for (int ni = 0; ni < 4; ni++) boff[ni] = (wn + ni * 16 + l16) * 64;
  sl[0] = ((0 + quad) ^ (l16 & 7)) * 8;
  sl[1] = ((4 + quad) ^ (l16 & 7)) * 8;

  floatx4 acc[4][4];
#pragma unroll
  for (int i = 0; i < 4; i++)
#pragma unroll
    for (int j = 0; j < 4; j++) acc[i][j] = (floatx4){0.f, 0.f, 0.f, 0.f};

  stage(0, 0);
  asm volatile("s_waitcnt vmcnt(0)" ::: "memory");
  __builtin_amdgcn_s_barrier();
  asm volatile("" ::: "memory");

  for (int i = 0; i < 16; i++) {
    if (i < 15) stage((i + 1) * 64, (i + 1) & 1);
    const u16* Ab = Al[i & 1];
    const u16* Bb = Bl[i & 1];
#pragma unroll
    for (int ks = 0; ks < 2; ks++) {
      bf16x8 af[4], bfr[4];
#pragma unroll
      for (int mi = 0; mi < 4; mi++)
        af[mi] = *reinterpret_cast<const bf16x8*>(Ab + aoff[mi] + sl[ks]);
#pragma unroll
      for (int ni = 0; ni < 4; ni++)
        bfr[ni] = *reinterpret_cast<const bf16x8*>(Bb + boff[ni] + sl[ks]);
      __builtin_amdgcn_s_setprio(1);
#pragma unroll
      for (int mi = 0; mi < 4; mi++)
#pragma unroll
        for (int ni = 0; ni < 4; ni++)
          acc[mi][ni] = MFMA16(af[mi], bfr[ni], acc[mi][ni]);
      __builtin_amdgcn_s_setprio(0);
    }
    if (i < 15) {
      asm volatile("s_waitcnt vmcnt(0)" ::: "memory");   // tile i+1 landed
      __builtin_amdgcn_s_barrier();
      asm volatile("" ::: "memory");
    }
  }

  if (MODE == 1) {
#pragma unroll
    for (int ni = 0; ni < 4; ni++) {
      int col = bn + wn + ni * 16 + l16;
      float bias = b0[col & 1023];
#pragma unroll
      for (int mi = 0; mi < 4; mi++)
#pragma unroll
        for (int r = 0; r < 4; r++) {
          int row = bm + wm + mi * 16 + quad * 4 + r;
          reinterpret_cast<float*>(Cv)[(size_t)row * ldc + col] = acc[mi][ni][r] + bias;
        }
    }
  } else {
    if (bn < 1024) {
      // V region: bf16 [8192][1024]
#pragma unroll
      for (int ni = 0; ni < 4; ni++) {
        int col = bn + wn + ni * 16 + l16;
        float bias = b0[col];
#pragma unroll
        for (int mi = 0; mi < 4; mi++)
#pragma unroll
          for (int r = 0; r < 4; r++) {
            int row = bm + wm + mi * 16 + quad * 4 + r;
            reinterpret_cast<u16*>(Cv)[(size_t)row * 1024 + col] =
                f2bf(acc[mi][ni][r] + bias);
          }
      }
    } else {
      // qlr/klr region: layout [bh][t][32]
      u16* outp = (bn < 1536) ? qo : ko;
      const float* bp = (bn < 1536) ? b1 : b2;
#pragma unroll
      for (int ni = 0; ni < 4; ni++) {
        int cc = (bn + wn + ni * 16 + l16) & 511;
        float bias = bp[cc];
        int hh = cc >> 5, rk = cc & 31;
#pragma unroll
        for (int mi = 0; mi < 4; mi++)
#pragma unroll
          for (int r = 0; r < 4; r++) {
            int row = bm + wm + mi * 16 + quad * 4 + r;
            size_t addr =
                ((size_t)((row >> 11) * 16 + hh) * 2048 + (row & 2047)) * 32 + rk;
            outp[addr] = f2bf(acc[mi][ni][r] + bias);
          }
      }
    }
  }
}

// ---------------- V transpose: vt[bh][d][t] ----------------
__global__ __launch_bounds__(256) void vtrans(const u16* __restrict__ V,
                                              u16* __restrict__ vt) {
  const int tb = blockIdx.x;
  const int bh = blockIdx.y;
  const int b = bh >> 4, h = bh & 15;
  __shared__ u16 Vl[64][72];
  const int tid = threadIdx.x;
#pragma unroll
  for (int it = 0; it < 2; it++) {
    int c = it * 256 + tid;
    int t = c >> 3, dc = (c & 7) * 8;
    u16x8 v = *reinterpret_cast<const u16x8*>(
        V + (size_t)(b * T_ + tb * 64 + t) * 1024 + h * 64 + dc);
    *reinterpret_cast<u16x8*>(&Vl[t][dc]) = v;
  }
  __syncthreads();
#pragma unroll
  for (int it = 0; it < 2; it++) {
    int c = it * 256 + tid;
    int d = c >> 3, tt = (c & 7) * 8;
    u16x8 o;
#pragma unroll
    for (int j = 0; j < 8; j++) o[j] = Vl[tt + j][d];
    *reinterpret_cast<u16x8*>(vt + ((size_t)bh * 64 + d) * T_ + tb * 64 + tt) = o;
  }
}

// ---------------- flash attention, S^T orientation, register-resident P ----------------
__global__ __launch_bounds__(256, 4) void attn(const u16* __restrict__ qlr,
                                               const u16* __restrict__ klr,
                                               const u16* __restrict__ vt,
                                               u16* __restrict__ yatt) {
  const int bh = blockIdx.y;
  const int b = bh >> 4, h = bh & 15;
  const int p = blockIdx.x;                       // pair index 0..15
  const int tid = threadIdx.x, lane = tid & 63, w = tid >> 6;
  const int quad = lane >> 4, l16 = lane & 15;

  __shared__ __align__(16) u16 Vt3[3][4096];      // 24 KB: V^T tiles [d=64][64 keys]
  __shared__ __align__(16) u16 Kt3[3][2048];      // 12 KB: K tiles   [64 keys][32 rk]

  const u16* qlr_bh = qlr + (size_t)bh * T_ * RK_;
  const u16* klr_bh = klr + (size_t)bh * T_ * RK_;
  const u16* vt_bh  = vt + (size_t)bh * 64 * T_;

  // hoisted V LDS read offsets: A-frag (nt,dt): d=dt*16+l16, keys nt*16+quad*4..+3
  int voff[4][4];
#pragma unroll
  for (int nt = 0; nt < 4; nt++)
#pragma unroll
    for (int dt = 0; dt < 4; dt++) {
      int d = dt * 16 + l16;
      voff[nt][dt] = d * 64 + (((nt * 2 + (quad >> 1)) ^ (d & 7)) * 8) + (quad & 1) * 4;
    }
  // V staging source offsets (pre-swizzled so linear LDS dest ends up swizzled)
  int soffV[2];
#pragma unroll
  for (int issue = 0; issue < 2; issue++) {
    int L = issue * 256 + tid;
    int d = L >> 3, cg = L & 7;
    soffV[issue] = d * T_ + ((cg ^ (d & 7)) * 8);
  }
  // K staging: 32 pair-rows (2 keys = 128B) x 8 slots of 16B, slot s <- src slot s^(pr&7)
  const int soffK = (w * 8 + (lane >> 3)) * 64 + (((lane & 7) ^ (lane >> 3)) * 8);
  // K read: key k=nt*16+l16, rk slot quad -> koff + nt*512
  const int koff = (l16 >> 1) * 64 + ((((l16 & 1) * 4 + quad) ^ (l16 >> 1)) * 8);
  const int wub = w * 512;

  const floatx4 fzero = {0.f, 0.f, 0.f, 0.f};

  for (int run = 0; run < 2; run++) {
    const int qi = run ? p : 31 - p;              // heavy q-tile first
    const int q0 = qi * 64;
    if (run) __syncthreads();                     // WAR fence before restaging buf0/1

    bf16x8 qf = *reinterpret_cast<const bf16x8*>(
        qlr_bh + (size_t)(q0 + w * 16 + l16) * 32 + quad * 8);

    auto stage = [&](int t, int bi) {             // 3 vmcnt ops per wave
      const u16* vs = vt_bh + t * 64;
      async_copy16(vs + soffV[0], &Vt3[bi][wub]);
      async_copy16(vs + soffV[1], &Vt3[bi][2048 + wub]);
      async_copy16(klr_bh + t * 2048 + soffK, &Kt3[bi][wub]);
    };

    stage(0, 0);
    if (qi >= 1) {
      stage(1, 1);
      asm volatile("s_waitcnt vmcnt(3)" ::: "memory");   // stage(0) landed
    } else {
      asm volatile("s_waitcnt vmcnt(0)" ::: "memory");
    }
    __builtin_amdgcn_s_barrier();
    asm volatile("" ::: "memory");                // no LDS reads hoist above barrier

    floatx4 oacc[4];
#pragma unroll
    for (int i = 0; i < 4; i++) oacc[i] = fzero;
    float rs = 0.f;

    const u16* Vb = &Vt3[0][0];
    const u16* Kb = &Kt3[0][0];
    int cb = 0, sb = 2;

    // ---- full tiles ----
    for (int i = 0; i < qi; i++) {
      const bool do_stage = (i + 2 <= qi);
      if (do_stage) stage(i + 2, sb);

      bf16x8 kf[4];
#pragma unroll
      for (int nt = 0; nt < 4; nt++)
        kf[nt] = *reinterpret_cast<const bf16x8*>(Kb + koff + nt * 512);
      floatx4 sv[4];
#pragma unroll
      for (int nt = 0; nt < 4; nt++) sv[nt] = MFMA16(kf[nt], qf, fzero);

      uint2 pk[4];
#pragma unroll
      for (int nt = 0; nt < 4; nt++) {
        float p0 = __builtin_amdgcn_exp2f(sv[nt][0]);
        float p1 = __builtin_amdgcn_exp2f(sv[nt][1]);
        float p2 = __builtin_amdgcn_exp2f(sv[nt][2]);
        float p3 = __builtin_amdgcn_exp2f(sv[nt][3]);
        rs += (p0 + p1) + (p2 + p3);
        pk[nt].x = tpack(p0, p1);
        pk[nt].y = tpack(p2, p3);
      }
#pragma unroll
      for (int dt = 0; dt < 4; dt++)
#pragma unroll
        for (int nt = 0; nt < 4; nt++) {
          s16x4 vf = *reinterpret_cast<const s16x4*>(Vb + voff[nt][dt]);
          oacc[dt] = MFMA1K(vf, __builtin_bit_cast(s16x4, pk[nt]), oacc[dt]);
        }

      // counted wait: stage(i+2) may stay in flight; stage(i+1) is done
      if (do_stage) asm volatile("s_waitcnt vmcnt(3)" ::: "memory");
      else          asm volatile("s_waitcnt vmcnt(0)" ::: "memory");
      __builtin_amdgcn_s_barrier();
      asm volatile("" ::: "memory");

      cb = (cb == 2) ? 0 : cb + 1;
      Vb = &Vt3[cb][0];
      Kb = &Kt3[cb][0];
      if (do_stage) sb = (sb == 2) ? 0 : sb + 1;
    }

    // ---- diagonal tile (masked) ----
    {
      bf16x8 kf[4];
#pragma unroll
      for (int nt = 0; nt < 4; nt++)
        kf[nt] = *reinterpret_cast<const bf16x8*>(Kb + koff + nt * 512);
      floatx4 sv[4];
#pragma unroll
      for (int nt = 0; nt < 4; nt++) sv[nt] = MFMA16(kf[nt], qf, fzero);
      const int thr = w * 16 + l16;
      uint2 pk[4];
#pragma unroll
      for (int nt = 0; nt < 4; nt++) {
        float pr[4];
#pragma unroll
        for (int r = 0; r < 4; r++) {
          float e = __builtin_amdgcn_exp2f(sv[nt][r]);
          pr[r] = (nt * 16 + quad * 4 + r <= thr) ? e : 0.f;
        }
        rs += (pr[0] + pr[1]) + (pr[2] + pr[3]);
        pk[nt].x = tpack(pr[0], pr[1]);
        pk[nt].y = tpack(pr[2], pr[3]);
      }
#pragma unroll
      for (int dt = 0; dt < 4; dt++)
#pragma unroll
        for (int nt = 0; nt < 4; nt++) {
          s16x4 vf = *reinterpret_cast<const s16x4*>(Vb + voff[nt][dt]);
          oacc[dt] = MFMA1K(vf, __builtin_bit_cast(s16x4, pk[nt]), oacc[dt]);
        }
    }

    // row-sum across the 4 quads; normalize; store O^T (d = dt*16+quad*4+r, qrow = l16)
    rs += __shfl_xor(rs, 16);
    rs += __shfl_xor(rs, 32);
    float inv = 1.f / rs;
    const int qrow = q0 + w * 16 + l16;
#pragma unroll
    for (int dt = 0; dt < 4; dt++) {
      uint2 ov = { pack_bf(oacc[dt][0] * inv, oacc[dt][1] * inv),
                   pack_bf(oacc[dt][2] * inv, oacc[dt][3] * inv) };
      *reinterpret_cast<uint2*>(
          yatt + (size_t)(b * T_ + qrow) * 1024 + h * 64 + dt * 16 + quad * 4) = ov;
    }
  }
}

// ---------------- launch ----------------
extern "C" void kernel_launch(void* const* d_in, const int* in_sizes, int n_in,
                              void* d_out, int out_size, void* d_ws, size_t ws_size,
                              hipStream_t stream) {
  const float* x   = (const float*)d_in[0];
  const float* Wq  = (const float*)d_in[1];
  const float* bq  = (const float*)d_in[2];
  const float* Wk  = (const float*)d_in[3];
  const float* bk  = (const float*)d_in[4];
  const float* Wv  = (const float*)d_in[5];
  const float* bv  = (const float*)d_in[6];
  const float* Wo  = (const float*)d_in[7];
  const float* bo  = (const float*)d_in[8];
  const float* Wql = (const float*)d_in[9];
  const float* Wkl = (const float*)d_in[10];
  float* out = (float*)d_out;

  char* ws = (char*)d_ws;
  u16*   xb    = (u16*)(ws);                  // 8192x1024 bf16 (16 MB) -- reused as vt
  u16*   Wcat  = (u16*)(ws + 16777216);       // 3072x1024 bf16 (6 MB): Wv | Weffq | Weffk | Wo
  float* beffq = (float*)(ws + 23068672);     // 512 f32
  float* beffk = (float*)(ws + 23072768);     // 512 f32
  u16*   Vbuf  = (u16*)(ws + 25165824);       // 8192x1024 bf16 (16 MB)
  u16*   qlr   = (u16*)(ws + 41943040);       // 64x2048x32 bf16 (8 MB)
  u16*   klr   = (u16*)(ws + 50331648);       // 64x2048x32 bf16 (8 MB)
  u16*   yatt  = (u16*)(ws + 58720256);       // 8192x1024 bf16 (16 MB)
  u16*   vt    = xb;                          // [bh][64][2048] bf16, after gemm0

  const float foldq = 0.25506100790944405f;   // (1/sqrt(32))*log2(e)

  cvt_x<<<dim3(8192), 256, 0, stream>>>(x, xb, 2097152);
  cvt_wvo<<<dim3(2048), 256, 0, stream>>>(Wv, Wo, Wcat);
  lsr_fold<<<dim3(512), 256, 0, stream>>>(Wq, bq, Wql, foldq, Wcat + 1048576, beffq);
  lsr_fold<<<dim3(512), 256, 0, stream>>>(Wk, bk, Wkl, 1.0f, Wcat + 1572864, beffk);
  gemm8<2><<<dim3(64, 16), 256, 0, stream>>>(xb, Wcat, bv, beffq, beffk,
                                             Vbuf, qlr, klr, 0);
  vtrans<<<dim3(32, 64), 256, 0, stream>>>(Vbuf, vt);
  attn<<<dim3(16, 64), 256, 0, stream>>>(qlr, klr, vt, yatt);
  gemm8<1><<<dim3(64, 8), 256, 0, stream>>>(yatt, Wcat + 2097152, bo, bo, bo,
                                            out, nullptr, nullptr, 1024);
}

// Round 5
// 235.254 us; speedup vs baseline: 1.2618x; 1.0256x over previous
//
#include <hip/hip_runtime.h>

#define B_  4
#define T_  2048
#define H_  16
#define DM_ 1024
#define DH_ 64
#define RK_ 32

using u16 = unsigned short;
using u32 = unsigned int;
typedef float  floatx4 __attribute__((ext_vector_type(4)));
typedef __bf16 bf16x8  __attribute__((ext_vector_type(8)));
typedef u16    u16x8   __attribute__((ext_vector_type(8)));
typedef u16    u16x4   __attribute__((ext_vector_type(4)));
typedef short  s16x4   __attribute__((ext_vector_type(4)));

#define MFMA16(a,b,c) __builtin_amdgcn_mfma_f32_16x16x32_bf16((a),(b),(c),0,0,0)
// K=16 bf16 MFMA: A/B frag = 4 bf16 (k = quad*4+j), C/D same 16x16 layout
#define MFMA1K(a,b,c) __builtin_amdgcn_mfma_f32_16x16x16bf16_1k((a),(b),(c),0,0,0)

__device__ __forceinline__ u16 f2bf(float f) {
  unsigned u = __float_as_uint(f);
  u += 0x7fffu + ((u >> 16) & 1u);   // RNE
  return (u16)(u >> 16);
}
// RNE pack: (bf16(b)<<16)|bf16(a)
__device__ __forceinline__ u32 pack_bf(float a, float b) {
  u32 ua = __float_as_uint(a); ua += 0x7fffu + ((ua >> 16) & 1u);
  u32 ub = __float_as_uint(b); ub += 0x7fffu + ((ub >> 16) & 1u);
  return __builtin_amdgcn_perm(ub, ua, 0x07060302u);
}
// truncation pack (1 instr) — for P in the hot loop (values > 0)
__device__ __forceinline__ u32 tpack(float a, float b) {
  return __builtin_amdgcn_perm(__float_as_uint(b), __float_as_uint(a), 0x07060302u);
}

// async global->LDS, 16B per lane. LDS dest is wave-uniform base; HW adds lane*16.
__device__ __forceinline__ void async_copy16(const u16* g, const u16* lds_uniform_base) {
  __builtin_amdgcn_global_load_lds(
      (const __attribute__((address_space(1))) unsigned int*)(unsigned long long)g,
      (__attribute__((address_space(3))) unsigned int*)(unsigned int)(unsigned long long)lds_uniform_base,
      16, 0, 0);
}

// ---------------- conversion kernels ----------------
__global__ __launch_bounds__(256) void cvt_x(const float* __restrict__ s,
                                             u16* __restrict__ d, int n4) {
  int i = blockIdx.x * 256 + threadIdx.x;
  if (i >= n4) return;
  float4 v = reinterpret_cast<const float4*>(s)[i];
  u16x4 o = { f2bf(v.x), f2bf(v.y), f2bf(v.z), f2bf(v.w) };
  reinterpret_cast<u16x4*>(d)[i] = o;
}

// Wv -> Wcat rows [0,1024); Wo -> Wcat rows [2048,3072)
__global__ __launch_bounds__(256) void cvt_wvo(const float* __restrict__ Wv,
                                               const float* __restrict__ Wo,
                                               u16* __restrict__ Wcat) {
  int i = blockIdx.x * 256 + threadIdx.x;       // 2 x 262144 float4-groups
  int reg = i >> 18;
  const float* s = reg ? Wo : Wv;
  int j = i & 262143;
  float4 v = reinterpret_cast<const float4*>(s)[j];
  u16x4 o = { f2bf(v.x), f2bf(v.y), f2bf(v.z), f2bf(v.w) };
  reinterpret_cast<u16x4*>(Wcat)[(reg ? 524288 : 0) + j] = o;
}

// ---------------- LSR weight folding ----------------
// Weff[hr][dm] = fold * sum_d lsr[h][d][r] * W[h*64+d][dm]   (bf16 out)
// beff[hr]    = fold * sum_d lsr[h][d][r] * bias[h*64+d]     (f32 out)
// => q_lr = x @ Weff^T + beff reproduces (x@W^T+b)@L exactly (up to rounding).
__global__ __launch_bounds__(256) void lsr_fold(const float* __restrict__ W,
                                                const float* __restrict__ bias,
                                                const float* __restrict__ lsr,
                                                float fold,
                                                u16* __restrict__ Weff,
                                                float* __restrict__ beff) {
  const int hr = blockIdx.x;                    // 0..511
  const int h = hr >> 5, r = hr & 31;
  const int tid = threadIdx.x;
  __shared__ float lw[64];
  if (tid < 64) lw[tid] = lsr[(size_t)(h * 64 + tid) * 32 + r] * fold;
  __syncthreads();
  float a0 = 0.f, a1 = 0.f, a2 = 0.f, a3 = 0.f;
  for (int d = 0; d < 64; d++) {
    float l = lw[d];
    float4 wv = *reinterpret_cast<const float4*>(W + (size_t)(h * 64 + d) * 1024 + tid * 4);
    a0 += l * wv.x; a1 += l * wv.y; a2 += l * wv.z; a3 += l * wv.w;
  }
  u16x4 o = { f2bf(a0), f2bf(a1), f2bf(a2), f2bf(a3) };
  reinterpret_cast<u16x4*>(Weff)[(size_t)hr * 256 + tid] = o;
  if (tid == 0) {
    float s = 0.f;
    for (int d = 0; d < 64; d++) s += lw[d] * bias[h * 64 + d];
    beff[hr] = s;
  }
}

// ---------------- GEMM: C[M,N] = A[M,K] * W[N,K]^T + bias, K=1024 ----------------
// 128x128 tile, BK=64, double-buffered 64KB LDS with XOR-swizzle (slot ^= row&7, T2):
// conflict-free ds_read_b128 (verified: SQ_LDS_BANK_CONFLICT = 0). Stage via
// global_load_lds with PRE-SWIZZLED global source (linear LDS dest, rule #21).
// Plain 2D grid (round-robin XCD on consecutive bm keeps A+W panels L2-resident;
// verified FETCH ~= ideal in round 3).
// MODE 1: f32 out to Cv (ldc), bias b0.
// MODE 2: fused QKV-LSR epilogue: cols [0,1024) -> V bf16 (Cv, ldc=1024, bias b0);
//         cols [1024,1536) -> qlr in attn layout (bias b1);
//         cols [1536,2048) -> klr in attn layout (bias b2).
template <int MODE>
__global__ __launch_bounds__(256, 2) void gemm8(const u16* __restrict__ A,
                                                const u16* __restrict__ W,
                                                const float* __restrict__ b0,
                                                const float* __restrict__ b1,
                                                const float* __restrict__ b2,
                                                void* __restrict__ Cv,
                                                u16* __restrict__ qo,
                                                u16* __restrict__ ko,
                                                int ldc) {
  __shared__ __align__(16) u16 Al[2][8192];   // [buf][128 rows][64 k] swizzled
  __shared__ __align__(16) u16 Bl[2][8192];
  const int tid  = threadIdx.x;
  const int lane = tid & 63;
  const int w    = tid >> 6;
  const int quad = lane >> 4;
  const int l16  = lane & 15;
  const int wm   = (w >> 1) << 6;
  const int wn   = (w & 1) << 6;

  const int bm = blockIdx.x << 7;
  const int bn = blockIdx.y << 7;

  // staging: thread tid covers LDS row (chunk*32 + tid>>3), slot tid&7.
  // source k-slot pre-swizzled so LDS slot s holds source slot s^(row&7).
  const int sr = tid >> 3;
  const int sc = ((tid & 7) ^ (sr & 7)) * 8;
  const u16* Ag = A + (size_t)(bm + sr) * 1024 + sc;
  const u16* Wg = W + (size_t)(bn + sr) * 1024 + sc;

  auto stage = [&](int k0, int bsel) {        // 8 vm ops / tile
#pragma unroll
    for (int j = 0; j < 4; j++)
      async_copy16(Ag + (size_t)j * 32768 + k0, &Al[bsel][j * 2048 + w * 512]);
#pragma unroll
    for (int j = 0; j < 4; j++)
      async_copy16(Wg + (size_t)j * 32768 + k0, &Bl[bsel][j * 2048 + w * 512]);
  };

  // fragment read offsets (u16): row*64 + ((ks*4+quad)^(row&7))*8, row&7 == l16&7
  int aoff[4], boff[4], sl[2];
#pragma unroll
  for (int mi = 0; mi < 4; mi++) aoff[mi] = (wm + mi * 16 + l16) * 64;
#pragma unroll
  for (int ni = 0; ni < 4; ni++) boff[ni] = (wn + ni * 16 + l16) * 64;
  sl[0] = ((0 + quad) ^ (l16 & 7)) * 8;
  sl[1] = ((4 + quad) ^ (l16 & 7)) * 8;

  floatx4 acc[4][4];
#pragma unroll
  for (int i = 0; i < 4; i++)
#pragma unroll
    for (int j = 0; j < 4; j++) acc[i][j] = (floatx4){0.f, 0.f, 0.f, 0.f};

  stage(0, 0);
  asm volatile("s_waitcnt vmcnt(0)" ::: "memory");
  __builtin_amdgcn_s_barrier();
  asm volatile("" ::: "memory");

  for (int i = 0; i < 16; i++) {
    if (i < 15) stage((i + 1) * 64, (i + 1) & 1);
    const u16* Ab = Al[i & 1];
    const u16* Bb = Bl[i & 1];
#pragma unroll
    for (int ks = 0; ks < 2; ks++) {
      bf16x8 af[4], bfr[4];
#pragma unroll
      for (int mi = 0; mi < 4; mi++)
        af[mi] = *reinterpret_cast<const bf16x8*>(Ab + aoff[mi] + sl[ks]);
#pragma unroll
      for (int ni = 0; ni < 4; ni++)
        bfr[ni] = *reinterpret_cast<const bf16x8*>(Bb + boff[ni] + sl[ks]);
      __builtin_amdgcn_s_setprio(1);
#pragma unroll
      for (int mi = 0; mi < 4; mi++)
#pragma unroll
        for (int ni = 0; ni < 4; ni++)
          acc[mi][ni] = MFMA16(af[mi], bfr[ni], acc[mi][ni]);
      __builtin_amdgcn_s_setprio(0);
    }
    if (i < 15) {
      asm volatile("s_waitcnt vmcnt(0)" ::: "memory");   // tile i+1 landed
      __builtin_amdgcn_s_barrier();
      asm volatile("" ::: "memory");
    }
  }

  if (MODE == 1) {
#pragma unroll
    for (int ni = 0; ni < 4; ni++) {
      int col = bn + wn + ni * 16 + l16;
      float bias = b0[col & 1023];
#pragma unroll
      for (int mi = 0; mi < 4; mi++)
#pragma unroll
        for (int r = 0; r < 4; r++) {
          int row = bm + wm + mi * 16 + quad * 4 + r;
          reinterpret_cast<float*>(Cv)[(size_t)row * ldc + col] = acc[mi][ni][r] + bias;
        }
    }
  } else {
    if (bn < 1024) {
      // V region: bf16 [8192][1024]
#pragma unroll
      for (int ni = 0; ni < 4; ni++) {
        int col = bn + wn + ni * 16 + l16;
        float bias = b0[col];
#pragma unroll
        for (int mi = 0; mi < 4; mi++)
#pragma unroll
          for (int r = 0; r < 4; r++) {
            int row = bm + wm + mi * 16 + quad * 4 + r;
            reinterpret_cast<u16*>(Cv)[(size_t)row * 1024 + col] =
                f2bf(acc[mi][ni][r] + bias);
          }
      }
    } else {
      // qlr/klr region: layout [bh][t][32]
      u16* outp = (bn < 1536) ? qo : ko;
      const float* bp = (bn < 1536) ? b1 : b2;
#pragma unroll
      for (int ni = 0; ni < 4; ni++) {
        int cc = (bn + wn + ni * 16 + l16) & 511;
        float bias = bp[cc];
        int hh = cc >> 5, rk = cc & 31;
#pragma unroll
        for (int mi = 0; mi < 4; mi++)
#pragma unroll
          for (int r = 0; r < 4; r++) {
            int row = bm + wm + mi * 16 + quad * 4 + r;
            size_t addr =
                ((size_t)((row >> 11) * 16 + hh) * 2048 + (row & 2047)) * 32 + rk;
            outp[addr] = f2bf(acc[mi][ni][r] + bias);
          }
      }
    }
  }
}

// ---------------- V transpose: vt[bh][d][t] ----------------
__global__ __launch_bounds__(256) void vtrans(const u16* __restrict__ V,
                                              u16* __restrict__ vt) {
  const int tb = blockIdx.x;
  const int bh = blockIdx.y;
  const int b = bh >> 4, h = bh & 15;
  __shared__ u16 Vl[64][72];
  const int tid = threadIdx.x;
#pragma unroll
  for (int it = 0; it < 2; it++) {
    int c = it * 256 + tid;
    int t = c >> 3, dc = (c & 7) * 8;
    u16x8 v = *reinterpret_cast<const u16x8*>(
        V + (size_t)(b * T_ + tb * 64 + t) * 1024 + h * 64 + dc);
    *reinterpret_cast<u16x8*>(&Vl[t][dc]) = v;
  }
  __syncthreads();
#pragma unroll
  for (int it = 0; it < 2; it++) {
    int c = it * 256 + tid;
    int d = c >> 3, tt = (c & 7) * 8;
    u16x8 o;
#pragma unroll
    for (int j = 0; j < 8; j++) o[j] = Vl[tt + j][d];
    *reinterpret_cast<u16x8*>(vt + ((size_t)bh * 64 + d) * T_ + tb * 64 + tt) = o;
  }
}

// ---------------- flash attention, S^T orientation, register-resident P ----------------
// Grid is (bh, p): linear id = bh + 64*p -> XCD = bh%8, so ALL 16 p-blocks of a head
// share one XCD; per-XCD K/V/Q working set = 8 bh x ~512 KB ~= 4MB L2 (L2-resident,
// fixes round-4's 143MB cross-XCD re-fetch). Paired q-tiles (31-p, p): uniform 33
// key-tiles/block. Depth-3 async pipeline, counted vmcnt(3), never drained mid-loop.
__global__ __launch_bounds__(256, 4) void attn(const u16* __restrict__ qlr,
                                               const u16* __restrict__ klr,
                                               const u16* __restrict__ vt,
                                               u16* __restrict__ yatt) {
  const int bh = blockIdx.x;                      // XCD = bh%8 under round-robin
  const int b = bh >> 4, h = bh & 15;
  const int p = blockIdx.y;                       // pair index 0..15
  const int tid = threadIdx.x, lane = tid & 63, w = tid >> 6;
  const int quad = lane >> 4, l16 = lane & 15;

  __shared__ __align__(16) u16 Vt3[3][4096];      // 24 KB: V^T tiles [d=64][64 keys]
  __shared__ __align__(16) u16 Kt3[3][2048];      // 12 KB: K tiles   [64 keys][32 rk]

  const u16* qlr_bh = qlr + (size_t)bh * T_ * RK_;
  const u16* klr_bh = klr + (size_t)bh * T_ * RK_;
  const u16* vt_bh  = vt + (size_t)bh * 64 * T_;

  // hoisted V LDS read offsets: A-frag (nt,dt): d=dt*16+l16, keys nt*16+quad*4..+3
  int voff[4][4];
#pragma unroll
  for (int nt = 0; nt < 4; nt++)
#pragma unroll
    for (int dt = 0; dt < 4; dt++) {
      int d = dt * 16 + l16;
      voff[nt][dt] = d * 64 + (((nt * 2 + (quad >> 1)) ^ (d & 7)) * 8) + (quad & 1) * 4;
    }
  // V staging source offsets (pre-swizzled so linear LDS dest ends up swizzled)
  int soffV[2];
#pragma unroll
  for (int issue = 0; issue < 2; issue++) {
    int L = issue * 256 + tid;
    int d = L >> 3, cg = L & 7;
    soffV[issue] = d * T_ + ((cg ^ (d & 7)) * 8);
  }
  // K staging: 32 pair-rows (2 keys = 128B) x 8 slots of 16B, slot s <- src slot s^(pr&7)
  const int soffK = (w * 8 + (lane >> 3)) * 64 + (((lane & 7) ^ (lane >> 3)) * 8);
  // K read: key k=nt*16+l16, rk slot quad -> koff + nt*512
  const int koff = (l16 >> 1) * 64 + ((((l16 & 1) * 4 + quad) ^ (l16 >> 1)) * 8);
  const int wub = w * 512;

  const floatx4 fzero = {0.f, 0.f, 0.f, 0.f};

  for (int run = 0; run < 2; run++) {
    const int qi = run ? p : 31 - p;              // heavy q-tile first
    const int q0 = qi * 64;
    if (run) __syncthreads();                     // WAR fence before restaging buf0/1

    bf16x8 qf = *reinterpret_cast<const bf16x8*>(
        qlr_bh + (size_t)(q0 + w * 16 + l16) * 32 + quad * 8);

    auto stage = [&](int t, int bi) {             // 3 vmcnt ops per wave
      const u16* vs = vt_bh + t * 64;
      async_copy16(vs + soffV[0], &Vt3[bi][wub]);
      async_copy16(vs + soffV[1], &Vt3[bi][2048 + wub]);
      async_copy16(klr_bh + t * 2048 + soffK, &Kt3[bi][wub]);
    };

    stage(0, 0);
    if (qi >= 1) {
      stage(1, 1);
      asm volatile("s_waitcnt vmcnt(3)" ::: "memory");   // stage(0) landed
    } else {
      asm volatile("s_waitcnt vmcnt(0)" ::: "memory");
    }
    __builtin_amdgcn_s_barrier();
    asm volatile("" ::: "memory");                // no LDS reads hoist above barrier

    floatx4 oacc[4];
#pragma unroll
    for (int i = 0; i < 4; i++) oacc[i] = fzero;
    float rs = 0.f;

    const u16* Vb = &Vt3[0][0];
    const u16* Kb = &Kt3[0][0];
    int cb = 0, sb = 2;

    // ---- full tiles ----
    for (int i = 0; i < qi; i++) {
      const bool do_stage = (i + 2 <= qi);
      if (do_stage) stage(i + 2, sb);

      bf16x8 kf[4];
#pragma unroll
      for (int nt = 0; nt < 4; nt++)
        kf[nt] = *reinterpret_cast<const bf16x8*>(Kb + koff + nt * 512);
      floatx4 sv[4];
      __builtin_amdgcn_s_setprio(1);
#pragma unroll
      for (int nt = 0; nt < 4; nt++) sv[nt] = MFMA16(kf[nt], qf, fzero);
      __builtin_amdgcn_s_setprio(0);

      uint2 pk[4];
#pragma unroll
      for (int nt = 0; nt < 4; nt++) {
        float p0 = __builtin_amdgcn_exp2f(sv[nt][0]);
        float p1 = __builtin_amdgcn_exp2f(sv[nt][1]);
        float p2 = __builtin_amdgcn_exp2f(sv[nt][2]);
        float p3 = __builtin_amdgcn_exp2f(sv[nt][3]);
        rs += (p0 + p1) + (p2 + p3);
        pk[nt].x = tpack(p0, p1);
        pk[nt].y = tpack(p2, p3);
      }
      __builtin_amdgcn_s_setprio(1);
#pragma unroll
      for (int dt = 0; dt < 4; dt++)
#pragma unroll
        for (int nt = 0; nt < 4; nt++) {
          s16x4 vf = *reinterpret_cast<const s16x4*>(Vb + voff[nt][dt]);
          oacc[dt] = MFMA1K(vf, __builtin_bit_cast(s16x4, pk[nt]), oacc[dt]);
        }
      __builtin_amdgcn_s_setprio(0);

      // counted wait: stage(i+2) may stay in flight; stage(i+1) is done
      if (do_stage) asm volatile("s_waitcnt vmcnt(3)" ::: "memory");
      else          asm volatile("s_waitcnt vmcnt(0)" ::: "memory");
      __builtin_amdgcn_s_barrier();
      asm volatile("" ::: "memory");

      cb = (cb == 2) ? 0 : cb + 1;
      Vb = &Vt3[cb][0];
      Kb = &Kt3[cb][0];
      if (do_stage) sb = (sb == 2) ? 0 : sb + 1;
    }

    // ---- diagonal tile (masked) ----
    {
      bf16x8 kf[4];
#pragma unroll
      for (int nt = 0; nt < 4; nt++)
        kf[nt] = *reinterpret_cast<const bf16x8*>(Kb + koff + nt * 512);
      floatx4 sv[4];
#pragma unroll
      for (int nt = 0; nt < 4; nt++) sv[nt] = MFMA16(kf[nt], qf, fzero);
      const int thr = w * 16 + l16;
      uint2 pk[4];
#pragma unroll
      for (int nt = 0; nt < 4; nt++) {
        float pr[4];
#pragma unroll
        for (int r = 0; r < 4; r++) {
          float e = __builtin_amdgcn_exp2f(sv[nt][r]);
          pr[r] = (nt * 16 + quad * 4 + r <= thr) ? e : 0.f;
        }
        rs += (pr[0] + pr[1]) + (pr[2] + pr[3]);
        pk[nt].x = tpack(pr[0], pr[1]);
        pk[nt].y = tpack(pr[2], pr[3]);
      }
      __builtin_amdgcn_s_setprio(1);
#pragma unroll
      for (int dt = 0; dt < 4; dt++)
#pragma unroll
        for (int nt = 0; nt < 4; nt++) {
          s16x4 vf = *reinterpret_cast<const s16x4*>(Vb + voff[nt][dt]);
          oacc[dt] = MFMA1K(vf, __builtin_bit_cast(s16x4, pk[nt]), oacc[dt]);
        }
      __builtin_amdgcn_s_setprio(0);
    }

    // row-sum across the 4 quads; normalize; store O^T (d = dt*16+quad*4+r, qrow = l16)
    rs += __shfl_xor(rs, 16);
    rs += __shfl_xor(rs, 32);
    float inv = 1.f / rs;
    const int qrow = q0 + w * 16 + l16;
#pragma unroll
    for (int dt = 0; dt < 4; dt++) {
      uint2 ov = { pack_bf(oacc[dt][0] * inv, oacc[dt][1] * inv),
                   pack_bf(oacc[dt][2] * inv, oacc[dt][3] * inv) };
      *reinterpret_cast<uint2*>(
          yatt + (size_t)(b * T_ + qrow) * 1024 + h * 64 + dt * 16 + quad * 4) = ov;
    }
  }
}

// ---------------- launch ----------------
extern "C" void kernel_launch(void* const* d_in, const int* in_sizes, int n_in,
                              void* d_out, int out_size, void* d_ws, size_t ws_size,
                              hipStream_t stream) {
  const float* x   = (const float*)d_in[0];
  const float* Wq  = (const float*)d_in[1];
  const float* bq  = (const float*)d_in[2];
  const float* Wk  = (const float*)d_in[3];
  const float* bk  = (const float*)d_in[4];
  const float* Wv  = (const float*)d_in[5];
  const float* bv  = (const float*)d_in[6];
  const float* Wo  = (const float*)d_in[7];
  const float* bo  = (const float*)d_in[8];
  const float* Wql = (const float*)d_in[9];
  const float* Wkl = (const float*)d_in[10];
  float* out = (float*)d_out;

  char* ws = (char*)d_ws;
  u16*   xb    = (u16*)(ws);                  // 8192x1024 bf16 (16 MB) -- reused as vt
  u16*   Wcat  = (u16*)(ws + 16777216);       // 3072x1024 bf16 (6 MB): Wv | Weffq | Weffk | Wo
  float* beffq = (float*)(ws + 23068672);     // 512 f32
  float* beffk = (float*)(ws + 23072768);     // 512 f32
  u16*   Vbuf  = (u16*)(ws + 25165824);       // 8192x1024 bf16 (16 MB)
  u16*   qlr   = (u16*)(ws + 41943040);       // 64x2048x32 bf16 (8 MB)
  u16*   klr   = (u16*)(ws + 50331648);       // 64x2048x32 bf16 (8 MB)
  u16*   yatt  = (u16*)(ws + 58720256);       // 8192x1024 bf16 (16 MB)
  u16*   vt    = xb;                          // [bh][64][2048] bf16, after gemm0

  const float foldq = 0.25506100790944405f;   // (1/sqrt(32))*log2(e)

  cvt_x<<<dim3(8192), 256, 0, stream>>>(x, xb, 2097152);
  cvt_wvo<<<dim3(2048), 256, 0, stream>>>(Wv, Wo, Wcat);
  lsr_fold<<<dim3(512), 256, 0, stream>>>(Wq, bq, Wql, foldq, Wcat + 1048576, beffq);
  lsr_fold<<<dim3(512), 256, 0, stream>>>(Wk, bk, Wkl, 1.0f, Wcat + 1572864, beffk);
  gemm8<2><<<dim3(64, 16), 256, 0, stream>>>(xb, Wcat, bv, beffq, beffk,
                                             Vbuf, qlr, klr, 0);
  vtrans<<<dim3(32, 64), 256, 0, stream>>>(Vbuf, vt);
  attn<<<dim3(64, 16), 256, 0, stream>>>(qlr, klr, vt, yatt);
  gemm8<1><<<dim3(64, 8), 256, 0, stream>>>(yatt, Wcat + 2097152, bo, bo, bo,
                                            out, nullptr, nullptr, 1024);
}